// Round 10
// baseline (294.541 us; speedup 1.0000x reference)
//
#include <hip/hip_runtime.h>
#include <hip/hip_bf16.h>

#define CH 64          // IN_C = HID_C = OUT_C = 64
#define BSH 9          // bucket shift: 512 nodes/bucket
#define CHUNK 16384    // edges per block in hist/scatter passes (1024 thr x 16)
#define MAXB 10240     // LDS col buffer (edges/bucket ~8163 +- 90)
#define NREP 4         // LDS histogram replicas (quarter-block each)
#define RPAD 257       // replica stride: 257 ints rotates bank mapping
// pairs packing: src < 2^17 (N=100000 <= 131072), dstLocal < 2^9 -> 26 bits
//
// SESSION LEDGER (hard-won):
//  R1/R2: 25k global atomicAdds to ONE cache line serialize cross-XCD = +276us.
//  R1:    x4-wide gather loads perf-NEUTRAL; gather NOT vmem-instr-rate bound.
//  R4:    in-wave GEMM via shfl+LDS = +96 DS ops/node = +88us.  DS-pipe
//         dependent chains are poison in gather epilogues.
//  R7:    masked 8-wide tail: gather 48.7->43.3us.  SERIAL LOAD-ROUNDS are
//         the gather lever (2.25->0.94 rounds = -11%).
//  R8:    4x hist replication: coarse/scatter -5us BUT scan 34->138us (one
//         L2 RTT per scan iter; unprovable-alias RMW doesn't pipeline).
//  R9:    scan rebuilt (4-group + 8-wide + parallel LDS scan): 138->~19us.
//         Total 269.6us.  gather_stats 44.3us VALU 63%.
//  R10:   this round — ONE masked 32-wide round/node (typical 2 serial
//         rounds -> 1); scan 16-wide; branchless rs[N]=E.
//  prev:  scalar s_load of col regressed; serial nodes/wave regressed 2.3x.

// ---------- CSR build: two-level counting sort, all atomics in LDS ----------

__global__ __launch_bounds__(1024)
void coarse_hist_kernel(const int* __restrict__ dst, int* __restrict__ blockHist,
                        int E, int nb) {
    __shared__ int h[NREP * RPAD];
    int t = threadIdx.x;
    int rep = t >> 8;
    for (int i = t; i < NREP * RPAD; i += 1024) h[i] = 0;
    __syncthreads();
    int* hr = h + rep * RPAD;
    int base = blockIdx.x * CHUNK + t * 16;
#pragma unroll
    for (int j = 0; j < 16; j += 4) {
        int e = base + j;
        if (e + 3 < E) {
            int4 d = *(const int4*)(dst + e);
            atomicAdd(&hr[d.x >> BSH], 1);
            atomicAdd(&hr[d.y >> BSH], 1);
            atomicAdd(&hr[d.z >> BSH], 1);
            atomicAdd(&hr[d.w >> BSH], 1);
        } else {
            for (int k = e; k < E && k < e + 4; ++k) atomicAdd(&hr[dst[k] >> BSH], 1);
        }
    }
    __syncthreads();
    for (int r = 0; r < NREP; ++r)
        for (int i = t; i < nb; i += 1024)
            blockHist[(blockIdx.x * NREP + r) * nb + i] = h[r * RPAD + i];
}

// R9 structure, R10: 16-wide batches (halve latency rounds).  4 groups x 256
// threads; group g owns vblk quarter [q0,q1).
__global__ __launch_bounds__(1024)
void scan_hist_kernel(int* __restrict__ blockHist, int* __restrict__ bucketStart,
                      int nblk, int nb) {
    __shared__ int qsum[NREP][256];
    __shared__ int tots[256];
    __shared__ int offs[256];
    int t = threadIdx.x;
    int g = t >> 8;        // quarter index 0..3
    int b = t & 255;       // bucket index
    int qlen = nblk / NREP;
    int q0 = g * qlen;
    int q1 = (g == NREP - 1) ? nblk : q0 + qlen;
    int s = 0;
    if (b < nb) {
        int blk = q0;
        for (; blk + 16 <= q1; blk += 16) {
            int v0 = blockHist[(blk + 0) * nb + b];
            int v1 = blockHist[(blk + 1) * nb + b];
            int v2 = blockHist[(blk + 2) * nb + b];
            int v3 = blockHist[(blk + 3) * nb + b];
            int v4 = blockHist[(blk + 4) * nb + b];
            int v5 = blockHist[(blk + 5) * nb + b];
            int v6 = blockHist[(blk + 6) * nb + b];
            int v7 = blockHist[(blk + 7) * nb + b];
            int v8 = blockHist[(blk + 8) * nb + b];
            int v9 = blockHist[(blk + 9) * nb + b];
            int va = blockHist[(blk + 10) * nb + b];
            int vb = blockHist[(blk + 11) * nb + b];
            int vc = blockHist[(blk + 12) * nb + b];
            int vd = blockHist[(blk + 13) * nb + b];
            int ve = blockHist[(blk + 14) * nb + b];
            int vf = blockHist[(blk + 15) * nb + b];
            s += v0 + v1 + v2 + v3 + v4 + v5 + v6 + v7
               + v8 + v9 + va + vb + vc + vd + ve + vf;
        }
        for (; blk < q1; ++blk) s += blockHist[blk * nb + b];
    }
    qsum[g][b] = s;
    __syncthreads();
    if (t < 256) {
        tots[t] = qsum[0][t] + qsum[1][t] + qsum[2][t] + qsum[3][t];
        offs[t] = tots[t];
    }
    __syncthreads();
    for (int off = 1; off < 256; off <<= 1) {
        int a = (t < 256 && t >= off) ? offs[t - off] : 0;
        __syncthreads();
        if (t < 256) offs[t] += a;
        __syncthreads();
    }
    // offs = inclusive scan of tots; exclusive = offs[b]-tots[b].
    if (b < nb) {
        int r = offs[b] - tots[b];
        for (int gg = 0; gg < g; ++gg) r += qsum[gg][b];
        int blk = q0;
        for (; blk + 16 <= q1; blk += 16) {
            int v0 = blockHist[(blk + 0) * nb + b];
            int v1 = blockHist[(blk + 1) * nb + b];
            int v2 = blockHist[(blk + 2) * nb + b];
            int v3 = blockHist[(blk + 3) * nb + b];
            int v4 = blockHist[(blk + 4) * nb + b];
            int v5 = blockHist[(blk + 5) * nb + b];
            int v6 = blockHist[(blk + 6) * nb + b];
            int v7 = blockHist[(blk + 7) * nb + b];
            int v8 = blockHist[(blk + 8) * nb + b];
            int v9 = blockHist[(blk + 9) * nb + b];
            int va = blockHist[(blk + 10) * nb + b];
            int vb = blockHist[(blk + 11) * nb + b];
            int vc = blockHist[(blk + 12) * nb + b];
            int vd = blockHist[(blk + 13) * nb + b];
            int ve = blockHist[(blk + 14) * nb + b];
            int vf = blockHist[(blk + 15) * nb + b];
            blockHist[(blk + 0) * nb + b] = r; r += v0;
            blockHist[(blk + 1) * nb + b] = r; r += v1;
            blockHist[(blk + 2) * nb + b] = r; r += v2;
            blockHist[(blk + 3) * nb + b] = r; r += v3;
            blockHist[(blk + 4) * nb + b] = r; r += v4;
            blockHist[(blk + 5) * nb + b] = r; r += v5;
            blockHist[(blk + 6) * nb + b] = r; r += v6;
            blockHist[(blk + 7) * nb + b] = r; r += v7;
            blockHist[(blk + 8) * nb + b] = r; r += v8;
            blockHist[(blk + 9) * nb + b] = r; r += v9;
            blockHist[(blk + 10) * nb + b] = r; r += va;
            blockHist[(blk + 11) * nb + b] = r; r += vb;
            blockHist[(blk + 12) * nb + b] = r; r += vc;
            blockHist[(blk + 13) * nb + b] = r; r += vd;
            blockHist[(blk + 14) * nb + b] = r; r += ve;
            blockHist[(blk + 15) * nb + b] = r; r += vf;
        }
        for (; blk < q1; ++blk) {
            int v = blockHist[blk * nb + b];
            blockHist[blk * nb + b] = r;
            r += v;
        }
    }
    if (t <= nb) bucketStart[t] = offs[t] - tots[t];  // tots[t]=0 for t>=nb
}

// pairs entry: (dstLocal << 17) | src.  Per-replica cursors (disjoint base
// ranges from the virtual-block scan) — within-bucket order is irrelevant.
__global__ __launch_bounds__(1024)
void scatter_pairs_kernel(const int* __restrict__ src, const int* __restrict__ dst,
                          const int* __restrict__ blockBase, unsigned* __restrict__ pairs,
                          int E, int nb) {
    __shared__ int cur[NREP * RPAD];
    int t = threadIdx.x;
    int rep = t >> 8;
    for (int r = 0; r < NREP; ++r)
        for (int i = t; i < nb; i += 1024)
            cur[r * RPAD + i] = blockBase[(blockIdx.x * NREP + r) * nb + i];
    __syncthreads();
    int* cr = cur + rep * RPAD;
    int base = blockIdx.x * CHUNK + t * 16;
#pragma unroll
    for (int j = 0; j < 16; j += 4) {
        int e = base + j;
        if (e + 3 < E) {
            int4 d = *(const int4*)(dst + e);
            int4 s = *(const int4*)(src + e);
            int p0 = atomicAdd(&cr[d.x >> BSH], 1);
            pairs[p0] = ((unsigned)(d.x & 511) << 17) | (unsigned)s.x;
            int p1 = atomicAdd(&cr[d.y >> BSH], 1);
            pairs[p1] = ((unsigned)(d.y & 511) << 17) | (unsigned)s.y;
            int p2 = atomicAdd(&cr[d.z >> BSH], 1);
            pairs[p2] = ((unsigned)(d.z & 511) << 17) | (unsigned)s.z;
            int p3 = atomicAdd(&cr[d.w >> BSH], 1);
            pairs[p3] = ((unsigned)(d.w & 511) << 17) | (unsigned)s.w;
        } else {
            for (int k = e; k < E && k < e + 4; ++k) {
                int d = dst[k];
                int p = atomicAdd(&cr[d >> BSH], 1);
                pairs[p] = ((unsigned)(d & 511) << 17) | (unsigned)src[k];
            }
        }
    }
}

__global__ __launch_bounds__(1024)
void bucket_csr_kernel(const unsigned* __restrict__ pairs, const int* __restrict__ bucketStart,
                       int* __restrict__ col, int* __restrict__ rs, float* __restrict__ dis,
                       int N, int nb, int E) {
    __shared__ int hist[512];
    __shared__ int offs[512];
    __shared__ int cursor[512];
    __shared__ int lcol[MAXB];
    int b = blockIdx.x;
    int t = threadIdx.x;
    int n0 = b << BSH;
    int nn = min(512, N - n0);
    int start = bucketStart[b];
    int endp = bucketStart[b + 1];
    int cnt = endp - start;
    bool big = cnt > MAXB;  // safety fallback: direct (uncoalesced) col writes
    for (int i = t; i < nn; i += 1024) hist[i] = 0;
    __syncthreads();
    for (int i = start + t; i < endp; i += 1024) {
        unsigned p = pairs[i];
        atomicAdd(&hist[p >> 17], 1);
    }
    __syncthreads();
    if (t < 512) offs[t] = (t < nn) ? hist[t] : 0;
    __syncthreads();
    for (int off = 1; off < 512; off <<= 1) {
        int a = (t < 512 && t >= off) ? offs[t - off] : 0;
        __syncthreads();
        if (t < 512) offs[t] += a;
        __syncthreads();
    }
    if (t < nn) {
        int excl = offs[t] - hist[t];          // exclusive scan value
        rs[n0 + t] = start + excl;
        dis[n0 + t] = rsqrtf((float)hist[t] + 1.0f);
        cursor[t] = excl;
    }
    if (b == 0 && t == 0) rs[N] = E;           // R10: branchless gather end
    __syncthreads();
    for (int i = start + t; i < endp; i += 1024) {
        unsigned p = pairs[i];
        int pos = atomicAdd(&cursor[p >> 17], 1);
        int sv = (int)(p & 0x1FFFFu);
        if (big) col[start + pos] = sv;
        else lcol[pos] = sv;
    }
    __syncthreads();
    if (!big) {
        for (int i = t; i < cnt; i += 1024) col[start + i] = lcol[i];
    }
}

// ---------- compute ----------

__device__ inline unsigned pack_bf2(float a, float b) {
    __hip_bfloat162 t;
    t.x = __float2bfloat16(a);
    t.y = __float2bfloat16(b);
    unsigned u;
    __builtin_memcpy(&u, &t, 4);
    return u;
}

__device__ inline float bf_lo(unsigned u) {
    unsigned w = u << 16; float f; __builtin_memcpy(&f, &w, 4); return f;
}
__device__ inline float bf_hi(unsigned u) {
    unsigned w = u & 0xffff0000u; float f; __builtin_memcpy(&f, &w, 4); return f;
}

// uniform-base + 32-bit byte-offset load -> global_load_dword v, voff, s[base]
__device__ inline unsigned ldu(const unsigned* p, unsigned boff) {
    return *(const unsigned*)((const char*)p + boff);
}

#define FMA32(x0, x1, x2, x3, wa, wb)                                        \
    a00 += (x0) * (wa).x; a01 += (x0) * (wa).y;                              \
    a02 += (x0) * (wa).z; a03 += (x0) * (wa).w;                              \
    a04 += (x0) * (wb).x; a05 += (x0) * (wb).y;                              \
    a06 += (x0) * (wb).z; a07 += (x0) * (wb).w;                              \
    a10 += (x1) * (wa).x; a11 += (x1) * (wa).y;                              \
    a12 += (x1) * (wa).z; a13 += (x1) * (wa).w;                              \
    a14 += (x1) * (wb).x; a15 += (x1) * (wb).y;                              \
    a16 += (x1) * (wb).z; a17 += (x1) * (wb).w;                              \
    a20 += (x2) * (wa).x; a21 += (x2) * (wa).y;                              \
    a22 += (x2) * (wa).z; a23 += (x2) * (wa).w;                              \
    a24 += (x2) * (wb).x; a25 += (x2) * (wb).y;                              \
    a26 += (x2) * (wb).z; a27 += (x2) * (wb).w;                              \
    a30 += (x3) * (wa).x; a31 += (x3) * (wa).y;                              \
    a32 += (x3) * (wa).z; a33 += (x3) * (wa).w;                              \
    a34 += (x3) * (wb).x; a35 += (x3) * (wb).y;                              \
    a36 += (x3) * (wb).z; a37 += (x3) * (wb).w;

// GEMM: 4 rows x 8 cols per thread (R1-R9: correctness-proven).  All named
// scalars.  unroll 2 under the 128-VGPR cap of (256,4).
__global__ __launch_bounds__(256, 4)
void gemm64_scaled_kernel(const float* __restrict__ X, const float* __restrict__ W,
                          const float* __restrict__ dis,
                          __hip_bfloat16* __restrict__ Y, int n) {
    __shared__ float Ws[CH * CH];
    {
        float4* w4 = (float4*)Ws;
        const float4* g4 = (const float4*)W;
        for (int i = threadIdx.x; i < CH * CH / 4; i += 256) w4[i] = g4[i];
    }
    __syncthreads();
    int t = threadIdx.x;
    int cbase = (t & 7) * 8;
    int r0 = blockIdx.x * 128 + (t >> 3) * 4;
    if (r0 >= n) return;
    int rB = min(r0 + 1, n - 1);
    int rC = min(r0 + 2, n - 1);
    int rD = min(r0 + 3, n - 1);
    const float4* pA = (const float4*)(X + (size_t)r0 * CH);
    const float4* pB = (const float4*)(X + (size_t)rB * CH);
    const float4* pC = (const float4*)(X + (size_t)rC * CH);
    const float4* pD = (const float4*)(X + (size_t)rD * CH);

    float a00 = 0.f, a01 = 0.f, a02 = 0.f, a03 = 0.f;
    float a04 = 0.f, a05 = 0.f, a06 = 0.f, a07 = 0.f;
    float a10 = 0.f, a11 = 0.f, a12 = 0.f, a13 = 0.f;
    float a14 = 0.f, a15 = 0.f, a16 = 0.f, a17 = 0.f;
    float a20 = 0.f, a21 = 0.f, a22 = 0.f, a23 = 0.f;
    float a24 = 0.f, a25 = 0.f, a26 = 0.f, a27 = 0.f;
    float a30 = 0.f, a31 = 0.f, a32 = 0.f, a33 = 0.f;
    float a34 = 0.f, a35 = 0.f, a36 = 0.f, a37 = 0.f;

#pragma unroll 2
    for (int k4 = 0; k4 < CH / 4; ++k4) {
        float4 xa = pA[k4];
        float4 xb = pB[k4];
        float4 xc = pC[k4];
        float4 xd = pD[k4];
        const float* wr = &Ws[(k4 * 4) * CH + cbase];
        float4 wa, wb;
        wa = *(const float4*)(wr);
        wb = *(const float4*)(wr + 4);
        FMA32(xa.x, xb.x, xc.x, xd.x, wa, wb)
        wa = *(const float4*)(wr + CH);
        wb = *(const float4*)(wr + CH + 4);
        FMA32(xa.y, xb.y, xc.y, xd.y, wa, wb)
        wa = *(const float4*)(wr + 2 * CH);
        wb = *(const float4*)(wr + 2 * CH + 4);
        FMA32(xa.z, xb.z, xc.z, xd.z, wa, wb)
        wa = *(const float4*)(wr + 3 * CH);
        wb = *(const float4*)(wr + 3 * CH + 4);
        FMA32(xa.w, xb.w, xc.w, xd.w, wa, wb)
    }

    uint4 pk;
    float d0 = dis[r0];
    pk.x = pack_bf2(a00 * d0, a01 * d0);
    pk.y = pack_bf2(a02 * d0, a03 * d0);
    pk.z = pack_bf2(a04 * d0, a05 * d0);
    pk.w = pack_bf2(a06 * d0, a07 * d0);
    *(uint4*)(Y + (size_t)r0 * CH + cbase) = pk;
    if (r0 + 1 < n) {
        float d1 = dis[r0 + 1];
        pk.x = pack_bf2(a10 * d1, a11 * d1);
        pk.y = pack_bf2(a12 * d1, a13 * d1);
        pk.z = pack_bf2(a14 * d1, a15 * d1);
        pk.w = pack_bf2(a16 * d1, a17 * d1);
        *(uint4*)(Y + (size_t)(r0 + 1) * CH + cbase) = pk;
    }
    if (r0 + 2 < n) {
        float d2 = dis[r0 + 2];
        pk.x = pack_bf2(a20 * d2, a21 * d2);
        pk.y = pack_bf2(a22 * d2, a23 * d2);
        pk.z = pack_bf2(a24 * d2, a25 * d2);
        pk.w = pack_bf2(a26 * d2, a27 * d2);
        *(uint4*)(Y + (size_t)(r0 + 2) * CH + cbase) = pk;
    }
    if (r0 + 3 < n) {
        float d3 = dis[r0 + 3];
        pk.x = pack_bf2(a30 * d3, a31 * d3);
        pk.y = pack_bf2(a32 * d3, a33 * d3);
        pk.z = pack_bf2(a34 * d3, a35 * d3);
        pk.w = pack_bf2(a36 * d3, a37 * d3);
        *(uint4*)(Y + (size_t)(r0 + 3) * CH + cbase) = pk;
    }
}

// R10 gather body: ONE masked 32-wide round per node (typical deg<=32) —
// 16 loads issued together, shfl indices clamped to cnt-1, invalid slots
// zeroed before accumulate (exact: bf_lo(0)=0; proven R7 pattern, widened).
// Full 32-rounds only for deg>32 (~10 nodes in 100k).  Serial rounds/node:
// ~1.94 -> ~1.0.
#define G32_OFF(K, IDX)                                                       \
    int i##K = eb + 2 * K + half;                                             \
    unsigned o##K = (unsigned)__shfl(myColB, (IDX), 64) | cp4;
#define G32_LOADS(CLAMP)                                                      \
    G32_OFF(0, CLAMP(0))  G32_OFF(1, CLAMP(1))  G32_OFF(2, CLAMP(2))          \
    G32_OFF(3, CLAMP(3))  G32_OFF(4, CLAMP(4))  G32_OFF(5, CLAMP(5))          \
    G32_OFF(6, CLAMP(6))  G32_OFF(7, CLAMP(7))  G32_OFF(8, CLAMP(8))          \
    G32_OFF(9, CLAMP(9))  G32_OFF(10, CLAMP(10)) G32_OFF(11, CLAMP(11))       \
    G32_OFF(12, CLAMP(12)) G32_OFF(13, CLAMP(13)) G32_OFF(14, CLAMP(14))      \
    G32_OFF(15, CLAMP(15))                                                    \
    unsigned u0 = ldu((XWSP), o0);   unsigned u1 = ldu((XWSP), o1);           \
    unsigned u2 = ldu((XWSP), o2);   unsigned u3 = ldu((XWSP), o3);           \
    unsigned u4 = ldu((XWSP), o4);   unsigned u5 = ldu((XWSP), o5);           \
    unsigned u6 = ldu((XWSP), o6);   unsigned u7 = ldu((XWSP), o7);           \
    unsigned u8 = ldu((XWSP), o8);   unsigned u9 = ldu((XWSP), o9);           \
    unsigned u10 = ldu((XWSP), o10); unsigned u11 = ldu((XWSP), o11);         \
    unsigned u12 = ldu((XWSP), o12); unsigned u13 = ldu((XWSP), o13);         \
    unsigned u14 = ldu((XWSP), o14); unsigned u15 = ldu((XWSP), o15);

#define CLAMP_FULL(K) (eb + 2 * K + half)
#define CLAMP_MASK(K) (min(eb + 2 * K + half, c1m))

#define GATHER_SHFL_BODY(XWS)                                                 \
    const unsigned* XWSP = (XWS);                                             \
    int beg = rs[wid];                                                        \
    int end = rs[wid + 1];                                                    \
    unsigned cp4 = (unsigned)cp << 2;                                         \
    float accx = 0.f, accy = 0.f;                                             \
    for (int base = beg; base < end; base += 64) {                            \
        int cnt = min(64, end - base);                                        \
        int myColB = (base + lane < end) ? (col[base + lane] << 7) : 0;       \
        int eb = 0;                                                           \
        for (; eb + 32 <= cnt; eb += 32) {  /* deg>32 only: full rounds */    \
            G32_LOADS(CLAMP_FULL)                                             \
            accx += bf_lo(u0) + bf_lo(u1) + bf_lo(u2) + bf_lo(u3);            \
            accy += bf_hi(u0) + bf_hi(u1) + bf_hi(u2) + bf_hi(u3);            \
            accx += bf_lo(u4) + bf_lo(u5) + bf_lo(u6) + bf_lo(u7);            \
            accy += bf_hi(u4) + bf_hi(u5) + bf_hi(u6) + bf_hi(u7);            \
            accx += bf_lo(u8) + bf_lo(u9) + bf_lo(u10) + bf_lo(u11);          \
            accy += bf_hi(u8) + bf_hi(u9) + bf_hi(u10) + bf_hi(u11);          \
            accx += bf_lo(u12) + bf_lo(u13) + bf_lo(u14) + bf_lo(u15);        \
            accy += bf_hi(u12) + bf_hi(u13) + bf_hi(u14) + bf_hi(u15);        \
        }                                                                     \
        int c1m = cnt - 1;                                                    \
        if (eb < cnt) {  /* ONE masked 32-wide round: the typical node */     \
            G32_LOADS(CLAMP_MASK)                                             \
            u0 = (i0 < cnt) ? u0 : 0u;    u1 = (i1 < cnt) ? u1 : 0u;          \
            u2 = (i2 < cnt) ? u2 : 0u;    u3 = (i3 < cnt) ? u3 : 0u;          \
            u4 = (i4 < cnt) ? u4 : 0u;    u5 = (i5 < cnt) ? u5 : 0u;          \
            u6 = (i6 < cnt) ? u6 : 0u;    u7 = (i7 < cnt) ? u7 : 0u;          \
            u8 = (i8 < cnt) ? u8 : 0u;    u9 = (i9 < cnt) ? u9 : 0u;          \
            u10 = (i10 < cnt) ? u10 : 0u; u11 = (i11 < cnt) ? u11 : 0u;       \
            u12 = (i12 < cnt) ? u12 : 0u; u13 = (i13 < cnt) ? u13 : 0u;       \
            u14 = (i14 < cnt) ? u14 : 0u; u15 = (i15 < cnt) ? u15 : 0u;       \
            accx += bf_lo(u0) + bf_lo(u1) + bf_lo(u2) + bf_lo(u3);            \
            accy += bf_hi(u0) + bf_hi(u1) + bf_hi(u2) + bf_hi(u3);            \
            accx += bf_lo(u4) + bf_lo(u5) + bf_lo(u6) + bf_lo(u7);            \
            accy += bf_hi(u4) + bf_hi(u5) + bf_hi(u6) + bf_hi(u7);            \
            accx += bf_lo(u8) + bf_lo(u9) + bf_lo(u10) + bf_lo(u11);          \
            accy += bf_hi(u8) + bf_hi(u9) + bf_hi(u10) + bf_hi(u11);          \
            accx += bf_lo(u12) + bf_lo(u13) + bf_lo(u14) + bf_lo(u15);        \
            accy += bf_hi(u12) + bf_hi(u13) + bf_hi(u14) + bf_hi(u15);        \
        }                                                                     \
    }                                                                         \
    accx += __shfl_xor(accx, 32, 64);                                         \
    accy += __shfl_xor(accy, 32, 64);

// Layer-1 gather: h[wid, 2cp]=vx, h[wid, 2cp+1]=vy (fp32, dense float2/lane).
// One node per wave (max TLP).  Self-term us/dd/bias hoisted BEFORE the edge
// loop so their latency overlaps it (R5, proven).
__global__ __launch_bounds__(256)
void gather_pair_kernel(const unsigned* __restrict__ xws, const int* __restrict__ col,
                        const int* __restrict__ rs, const float* __restrict__ dis,
                        const float* __restrict__ b1, float* __restrict__ h,
                        int n, int E) {
    int wid = blockIdx.x * 4 + (threadIdx.x >> 6);
    int lane = threadIdx.x & 63;
    int cp = lane & 31;
    int half = lane >> 5;
    if (wid >= n) return;

    unsigned us = xws[(size_t)wid * 32 + cp];   // hoisted: overlaps gather
    float dd = dis[wid];
    float2 bb = ((const float2*)b1)[cp];

    GATHER_SHFL_BODY(xws)

    if (half == 0) {
        float2 o;
        o.x = fmaxf(dd * (accx + bf_lo(us)) + bb.x, 0.f);
        o.y = fmaxf(dd * (accy + bf_hi(us)) + bb.y, 0.f);
        ((float2*)h)[(size_t)wid * 32 + cp] = o;  // 8B/lane, dense 256B
    }
}

// Layer-2 gather + relu + per-block LN partials (NON-atomic per-block stores
// + 1-block reduce — R1/R2 lesson).
__global__ __launch_bounds__(256)
void gather_stats_kernel(const unsigned* __restrict__ xws, const int* __restrict__ col,
                         const int* __restrict__ rs, const float* __restrict__ dis,
                         const float* __restrict__ b2, float* __restrict__ out,
                         int n, int E, float* __restrict__ sums, float* __restrict__ sqs) {
    int wid = blockIdx.x * 4 + (threadIdx.x >> 6);
    int lane = threadIdx.x & 63;
    int cp = lane & 31;
    int half = lane >> 5;
    float vx = 0.f, vy = 0.f;
    if (wid < n) {
        unsigned us = xws[(size_t)wid * 32 + cp];   // hoisted
        float dd = dis[wid];
        float2 bb = ((const float2*)b2)[cp];
        GATHER_SHFL_BODY(xws)
        vx = fmaxf(dd * (accx + bf_lo(us)) + bb.x, 0.f);
        vy = fmaxf(dd * (accy + bf_hi(us)) + bb.y, 0.f);
        if (half == 0) {
            float2 o; o.x = vx; o.y = vy;
            ((float2*)out)[(size_t)wid * 32 + cp] = o;
        }
    }
    float s = (half == 0) ? vx + vy : 0.f;
    float sq = (half == 0) ? vx * vx + vy * vy : 0.f;
#pragma unroll
    for (int off = 32; off > 0; off >>= 1) {
        s += __shfl_down(s, off, 64);
        sq += __shfl_down(sq, off, 64);
    }
    __shared__ float ls[4], lq[4];
    int w = threadIdx.x >> 6;
    if ((threadIdx.x & 63) == 0) { ls[w] = s; lq[w] = sq; }
    __syncthreads();
    if (threadIdx.x == 0) {
        sums[blockIdx.x] = ls[0] + ls[1] + ls[2] + ls[3];
        sqs[blockIdx.x] = lq[0] + lq[1] + lq[2] + lq[3];
    }
}

__global__ void reduce_final_kernel(const float* __restrict__ sums, const float* __restrict__ sqs,
                                    int nb, float n_total, const float* __restrict__ lnw,
                                    const float* __restrict__ lnb, float* __restrict__ so) {
    float s = 0.0f, sq = 0.0f;
    for (int i = threadIdx.x; i < nb; i += 1024) { s += sums[i]; sq += sqs[i]; }
#pragma unroll
    for (int off = 32; off > 0; off >>= 1) {
        s += __shfl_down(s, off, 64);
        sq += __shfl_down(sq, off, 64);
    }
    __shared__ float ls[16], lq[16];
    int w = threadIdx.x >> 6;
    if ((threadIdx.x & 63) == 0) { ls[w] = s; lq[w] = sq; }
    __syncthreads();
    if (threadIdx.x == 0) {
        float ts = 0.0f, tq = 0.0f;
        for (int i = 0; i < 16; ++i) { ts += ls[i]; tq += lq[i]; }
        float mean = ts / n_total;
        float var = tq / n_total - mean * mean;
        float scale = rsqrtf(var + 1e-5f) * lnw[0];
        so[0] = scale;
        so[1] = lnb[0] - mean * scale;
    }
}

// 32B/thread (2x float4): halves block count vs 16B/thread.
__global__ void norm_kernel(float* __restrict__ x, int n8, const float* __restrict__ so) {
    int i = blockIdx.x * blockDim.x + threadIdx.x;
    if (i >= n8) return;
    float scale = so[0], off = so[1];
    float4* x4 = (float4*)x;
    float4 a = x4[2 * i];
    float4 b = x4[2 * i + 1];
    a.x = a.x * scale + off; a.y = a.y * scale + off;
    a.z = a.z * scale + off; a.w = a.w * scale + off;
    b.x = b.x * scale + off; b.y = b.y * scale + off;
    b.z = b.z * scale + off; b.w = b.w * scale + off;
    x4[2 * i] = a;
    x4[2 * i + 1] = b;
}

extern "C" void kernel_launch(void* const* d_in, const int* in_sizes, int n_in,
                              void* d_out, int out_size, void* d_ws, size_t ws_size,
                              hipStream_t stream) {
    const float* X   = (const float*)d_in[0];
    const int*   edg = (const int*)d_in[1];   // [2,E]: src row then dst row
    const float* W1  = (const float*)d_in[2];
    const float* b1  = (const float*)d_in[3];
    const float* W2  = (const float*)d_in[4];
    const float* b2  = (const float*)d_in[5];
    const float* lnw = (const float*)d_in[6];
    const float* lnb = (const float*)d_in[7];
    float* out = (float*)d_out;

    const int N  = in_sizes[0] / CH;   // 100000
    const int E  = in_sizes[1] / 2;    // 1600000
    const int NC = N * CH;             // 6.4M
    const int nNodeBlk = (N + 3) / 4;  // 25000 (4 nodes / block)
    const int nb = (N + 511) >> BSH;   // 196 buckets
    const int nblkE = (E + CHUNK - 1) / CHUNK;  // 98 edge-chunk blocks
    const int nvblk = nblkE * NREP;    // 392 virtual hist blocks

    const int* srcp = edg;
    const int* dstp = edg + E;

    // workspace layout (4B units).  pairs (E unsigned) dead after bucket_csr;
    // h (NC floats) overlays it.  rs is N+1 (rs[N]=E, R10 branchless end).
    int*   col   = (int*)d_ws;                          // E
    int*   rs    = col + E;                             // N+1
    float* dis   = (float*)(rs + N + 1);                // N
    __hip_bfloat16* xws1 = (__hip_bfloat16*)(dis + N);  // NC bf16
    __hip_bfloat16* xws2 = xws1 + NC;                   // NC bf16
    float* h     = (float*)(xws2 + NC);                 // NC floats
    unsigned* pairs = (unsigned*)h;                     // E u32 (dead before h live)
    int*   bHist = (int*)(h + NC);                      // nvblk*nb
    int*   bStart= bHist + nvblk * nb;                  // nb+1
    float* sums  = (float*)(bStart + nb + 1);           // nNodeBlk
    float* sqs   = sums + nNodeBlk;                     // nNodeBlk
    float* so    = sqs + nNodeBlk;                      // 2 {scale, offset}

    const int B = 256;
    const int nGemmBlk = (N + 127) / 128;               // 782 (4 rows/thread)

    // ---- CSR build (no global atomics, no memset) ----
    coarse_hist_kernel<<<nblkE, 1024, 0, stream>>>(dstp, bHist, E, nb);
    scan_hist_kernel<<<1, 1024, 0, stream>>>(bHist, bStart, nvblk, nb);
    scatter_pairs_kernel<<<nblkE, 1024, 0, stream>>>(srcp, dstp, bHist, pairs, E, nb);
    bucket_csr_kernel<<<nb, 1024, 0, stream>>>(pairs, bStart, col, rs, dis, N, nb, E);
    // rs = row_start; row i spans [rs[i], rs[i+1]); rs[N] = E

    // ---- layer 1 ----
    gemm64_scaled_kernel<<<nGemmBlk, B, 0, stream>>>(X, W1, dis, xws1, N);
    gather_pair_kernel<<<nNodeBlk, B, 0, stream>>>((const unsigned*)xws1, col, rs, dis,
                                                   b1, h, N, E);

    // ---- layer 2 ----
    gemm64_scaled_kernel<<<nGemmBlk, B, 0, stream>>>(h, W2, dis, xws2, N);
    gather_stats_kernel<<<nNodeBlk, B, 0, stream>>>((const unsigned*)xws2, col, rs, dis,
                                                    b2, out, N, E, sums, sqs);

    // ---- graph layernorm ----
    reduce_final_kernel<<<1, 1024, 0, stream>>>(sums, sqs, nNodeBlk, (float)NC, lnw, lnb, so);
    norm_kernel<<<(NC / 8 + B - 1) / B, B, 0, stream>>>(out, NC / 8, so);
}

// Round 11
// 290.358 us; speedup vs baseline: 1.0144x; 1.0144x over previous
//
#include <hip/hip_runtime.h>
#include <hip/hip_bf16.h>

#define CH 64          // IN_C = HID_C = OUT_C = 64
#define BSH 9          // bucket shift: 512 nodes/bucket
#define CHUNK 16384    // edges per block in hist/scatter passes (1024 thr x 16)
#define MAXB 10240     // LDS col buffer (edges/bucket ~8163 +- 90)
#define NREP 4         // LDS histogram replicas (quarter-block each)
#define RPAD 257       // replica stride: 257 ints rotates bank mapping
// pairs packing: src < 2^17 (N=100000 <= 131072), dstLocal < 2^9 -> 26 bits
//
// SESSION LEDGER (hard-won):
//  R1/R2: 25k global atomicAdds to ONE cache line serialize cross-XCD = +276us.
//  R4:    in-wave GEMM via shfl+LDS = +96 DS ops/node = +88us.  DS-pipe
//         dependent chains are poison in gather epilogues.
//  R7:    masked 8-wide tail: gather 48.7->43.3us.  Serial load-rounds are
//         the gather lever WHEN load count is constant.
//  R8/R9: 4x hist replication helps coarse/scatter (-5us); scan must be
//         chain-free (4-group + wide batches + parallel LDS scan).
//  R10:   masked-32 round: +50% issued loads -> FETCH 88->157MB, BW hit
//         3.54TB/s ceiling, gather 44.3->53.2us.  FETCH TRACKS ISSUED
//         LOADS (clamped dups NOT free).  Minimize loads FIRST, then
//         serial rounds.
//  R11:   this round — R7 load count exactly + ONE-round tail (branch:
//         r>8 -> masked-16, else masked-8; wave-uniform branch).
//  prev:  scalar s_load of col regressed; serial nodes/wave regressed 2.3x.

// ---------- CSR build: two-level counting sort, all atomics in LDS ----------

__global__ __launch_bounds__(1024)
void coarse_hist_kernel(const int* __restrict__ dst, int* __restrict__ blockHist,
                        int E, int nb) {
    __shared__ int h[NREP * RPAD];
    int t = threadIdx.x;
    int rep = t >> 8;
    for (int i = t; i < NREP * RPAD; i += 1024) h[i] = 0;
    __syncthreads();
    int* hr = h + rep * RPAD;
    int base = blockIdx.x * CHUNK + t * 16;
#pragma unroll
    for (int j = 0; j < 16; j += 4) {
        int e = base + j;
        if (e + 3 < E) {
            int4 d = *(const int4*)(dst + e);
            atomicAdd(&hr[d.x >> BSH], 1);
            atomicAdd(&hr[d.y >> BSH], 1);
            atomicAdd(&hr[d.z >> BSH], 1);
            atomicAdd(&hr[d.w >> BSH], 1);
        } else {
            for (int k = e; k < E && k < e + 4; ++k) atomicAdd(&hr[dst[k] >> BSH], 1);
        }
    }
    __syncthreads();
    for (int r = 0; r < NREP; ++r)
        for (int i = t; i < nb; i += 1024)
            blockHist[(blockIdx.x * NREP + r) * nb + i] = h[r * RPAD + i];
}

// 4 groups x 256 threads; group g owns vblk quarter [q0,q1); 16-wide batches.
__global__ __launch_bounds__(1024)
void scan_hist_kernel(int* __restrict__ blockHist, int* __restrict__ bucketStart,
                      int nblk, int nb) {
    __shared__ int qsum[NREP][256];
    __shared__ int tots[256];
    __shared__ int offs[256];
    int t = threadIdx.x;
    int g = t >> 8;        // quarter index 0..3
    int b = t & 255;       // bucket index
    int qlen = nblk / NREP;
    int q0 = g * qlen;
    int q1 = (g == NREP - 1) ? nblk : q0 + qlen;
    int s = 0;
    if (b < nb) {
        int blk = q0;
        for (; blk + 16 <= q1; blk += 16) {
            int v0 = blockHist[(blk + 0) * nb + b];
            int v1 = blockHist[(blk + 1) * nb + b];
            int v2 = blockHist[(blk + 2) * nb + b];
            int v3 = blockHist[(blk + 3) * nb + b];
            int v4 = blockHist[(blk + 4) * nb + b];
            int v5 = blockHist[(blk + 5) * nb + b];
            int v6 = blockHist[(blk + 6) * nb + b];
            int v7 = blockHist[(blk + 7) * nb + b];
            int v8 = blockHist[(blk + 8) * nb + b];
            int v9 = blockHist[(blk + 9) * nb + b];
            int va = blockHist[(blk + 10) * nb + b];
            int vb = blockHist[(blk + 11) * nb + b];
            int vc = blockHist[(blk + 12) * nb + b];
            int vd = blockHist[(blk + 13) * nb + b];
            int ve = blockHist[(blk + 14) * nb + b];
            int vf = blockHist[(blk + 15) * nb + b];
            s += v0 + v1 + v2 + v3 + v4 + v5 + v6 + v7
               + v8 + v9 + va + vb + vc + vd + ve + vf;
        }
        for (; blk < q1; ++blk) s += blockHist[blk * nb + b];
    }
    qsum[g][b] = s;
    __syncthreads();
    if (t < 256) {
        tots[t] = qsum[0][t] + qsum[1][t] + qsum[2][t] + qsum[3][t];
        offs[t] = tots[t];
    }
    __syncthreads();
    for (int off = 1; off < 256; off <<= 1) {
        int a = (t < 256 && t >= off) ? offs[t - off] : 0;
        __syncthreads();
        if (t < 256) offs[t] += a;
        __syncthreads();
    }
    // offs = inclusive scan of tots; exclusive = offs[b]-tots[b].
    if (b < nb) {
        int r = offs[b] - tots[b];
        for (int gg = 0; gg < g; ++gg) r += qsum[gg][b];
        int blk = q0;
        for (; blk + 16 <= q1; blk += 16) {
            int v0 = blockHist[(blk + 0) * nb + b];
            int v1 = blockHist[(blk + 1) * nb + b];
            int v2 = blockHist[(blk + 2) * nb + b];
            int v3 = blockHist[(blk + 3) * nb + b];
            int v4 = blockHist[(blk + 4) * nb + b];
            int v5 = blockHist[(blk + 5) * nb + b];
            int v6 = blockHist[(blk + 6) * nb + b];
            int v7 = blockHist[(blk + 7) * nb + b];
            int v8 = blockHist[(blk + 8) * nb + b];
            int v9 = blockHist[(blk + 9) * nb + b];
            int va = blockHist[(blk + 10) * nb + b];
            int vb = blockHist[(blk + 11) * nb + b];
            int vc = blockHist[(blk + 12) * nb + b];
            int vd = blockHist[(blk + 13) * nb + b];
            int ve = blockHist[(blk + 14) * nb + b];
            int vf = blockHist[(blk + 15) * nb + b];
            blockHist[(blk + 0) * nb + b] = r; r += v0;
            blockHist[(blk + 1) * nb + b] = r; r += v1;
            blockHist[(blk + 2) * nb + b] = r; r += v2;
            blockHist[(blk + 3) * nb + b] = r; r += v3;
            blockHist[(blk + 4) * nb + b] = r; r += v4;
            blockHist[(blk + 5) * nb + b] = r; r += v5;
            blockHist[(blk + 6) * nb + b] = r; r += v6;
            blockHist[(blk + 7) * nb + b] = r; r += v7;
            blockHist[(blk + 8) * nb + b] = r; r += v8;
            blockHist[(blk + 9) * nb + b] = r; r += v9;
            blockHist[(blk + 10) * nb + b] = r; r += va;
            blockHist[(blk + 11) * nb + b] = r; r += vb;
            blockHist[(blk + 12) * nb + b] = r; r += vc;
            blockHist[(blk + 13) * nb + b] = r; r += vd;
            blockHist[(blk + 14) * nb + b] = r; r += ve;
            blockHist[(blk + 15) * nb + b] = r; r += vf;
        }
        for (; blk < q1; ++blk) {
            int v = blockHist[blk * nb + b];
            blockHist[blk * nb + b] = r;
            r += v;
        }
    }
    if (t <= nb) bucketStart[t] = offs[t] - tots[t];  // tots[t]=0 for t>=nb
}

// pairs entry: (dstLocal << 17) | src.  Per-replica cursors (disjoint base
// ranges from the virtual-block scan) — within-bucket order is irrelevant.
__global__ __launch_bounds__(1024)
void scatter_pairs_kernel(const int* __restrict__ src, const int* __restrict__ dst,
                          const int* __restrict__ blockBase, unsigned* __restrict__ pairs,
                          int E, int nb) {
    __shared__ int cur[NREP * RPAD];
    int t = threadIdx.x;
    int rep = t >> 8;
    for (int r = 0; r < NREP; ++r)
        for (int i = t; i < nb; i += 1024)
            cur[r * RPAD + i] = blockBase[(blockIdx.x * NREP + r) * nb + i];
    __syncthreads();
    int* cr = cur + rep * RPAD;
    int base = blockIdx.x * CHUNK + t * 16;
#pragma unroll
    for (int j = 0; j < 16; j += 4) {
        int e = base + j;
        if (e + 3 < E) {
            int4 d = *(const int4*)(dst + e);
            int4 s = *(const int4*)(src + e);
            int p0 = atomicAdd(&cr[d.x >> BSH], 1);
            pairs[p0] = ((unsigned)(d.x & 511) << 17) | (unsigned)s.x;
            int p1 = atomicAdd(&cr[d.y >> BSH], 1);
            pairs[p1] = ((unsigned)(d.y & 511) << 17) | (unsigned)s.y;
            int p2 = atomicAdd(&cr[d.z >> BSH], 1);
            pairs[p2] = ((unsigned)(d.z & 511) << 17) | (unsigned)s.z;
            int p3 = atomicAdd(&cr[d.w >> BSH], 1);
            pairs[p3] = ((unsigned)(d.w & 511) << 17) | (unsigned)s.w;
        } else {
            for (int k = e; k < E && k < e + 4; ++k) {
                int d = dst[k];
                int p = atomicAdd(&cr[d >> BSH], 1);
                pairs[p] = ((unsigned)(d & 511) << 17) | (unsigned)src[k];
            }
        }
    }
}

__global__ __launch_bounds__(1024)
void bucket_csr_kernel(const unsigned* __restrict__ pairs, const int* __restrict__ bucketStart,
                       int* __restrict__ col, int* __restrict__ rs, float* __restrict__ dis,
                       int N, int nb, int E) {
    __shared__ int hist[512];
    __shared__ int offs[512];
    __shared__ int cursor[512];
    __shared__ int lcol[MAXB];
    int b = blockIdx.x;
    int t = threadIdx.x;
    int n0 = b << BSH;
    int nn = min(512, N - n0);
    int start = bucketStart[b];
    int endp = bucketStart[b + 1];
    int cnt = endp - start;
    bool big = cnt > MAXB;  // safety fallback: direct (uncoalesced) col writes
    for (int i = t; i < nn; i += 1024) hist[i] = 0;
    __syncthreads();
    for (int i = start + t; i < endp; i += 1024) {
        unsigned p = pairs[i];
        atomicAdd(&hist[p >> 17], 1);
    }
    __syncthreads();
    if (t < 512) offs[t] = (t < nn) ? hist[t] : 0;
    __syncthreads();
    for (int off = 1; off < 512; off <<= 1) {
        int a = (t < 512 && t >= off) ? offs[t - off] : 0;
        __syncthreads();
        if (t < 512) offs[t] += a;
        __syncthreads();
    }
    if (t < nn) {
        int excl = offs[t] - hist[t];          // exclusive scan value
        rs[n0 + t] = start + excl;
        dis[n0 + t] = rsqrtf((float)hist[t] + 1.0f);
        cursor[t] = excl;
    }
    if (b == 0 && t == 0) rs[N] = E;           // branchless gather end
    __syncthreads();
    for (int i = start + t; i < endp; i += 1024) {
        unsigned p = pairs[i];
        int pos = atomicAdd(&cursor[p >> 17], 1);
        int sv = (int)(p & 0x1FFFFu);
        if (big) col[start + pos] = sv;
        else lcol[pos] = sv;
    }
    __syncthreads();
    if (!big) {
        for (int i = t; i < cnt; i += 1024) col[start + i] = lcol[i];
    }
}

// ---------- compute ----------

__device__ inline unsigned pack_bf2(float a, float b) {
    __hip_bfloat162 t;
    t.x = __float2bfloat16(a);
    t.y = __float2bfloat16(b);
    unsigned u;
    __builtin_memcpy(&u, &t, 4);
    return u;
}

__device__ inline float bf_lo(unsigned u) {
    unsigned w = u << 16; float f; __builtin_memcpy(&f, &w, 4); return f;
}
__device__ inline float bf_hi(unsigned u) {
    unsigned w = u & 0xffff0000u; float f; __builtin_memcpy(&f, &w, 4); return f;
}

// uniform-base + 32-bit byte-offset load -> global_load_dword v, voff, s[base]
__device__ inline unsigned ldu(const unsigned* p, unsigned boff) {
    return *(const unsigned*)((const char*)p + boff);
}

#define FMA32(x0, x1, x2, x3, wa, wb)                                        \
    a00 += (x0) * (wa).x; a01 += (x0) * (wa).y;                              \
    a02 += (x0) * (wa).z; a03 += (x0) * (wa).w;                              \
    a04 += (x0) * (wb).x; a05 += (x0) * (wb).y;                              \
    a06 += (x0) * (wb).z; a07 += (x0) * (wb).w;                              \
    a10 += (x1) * (wa).x; a11 += (x1) * (wa).y;                              \
    a12 += (x1) * (wa).z; a13 += (x1) * (wa).w;                              \
    a14 += (x1) * (wb).x; a15 += (x1) * (wb).y;                              \
    a16 += (x1) * (wb).z; a17 += (x1) * (wb).w;                              \
    a20 += (x2) * (wa).x; a21 += (x2) * (wa).y;                              \
    a22 += (x2) * (wa).z; a23 += (x2) * (wa).w;                              \
    a24 += (x2) * (wb).x; a25 += (x2) * (wb).y;                              \
    a26 += (x2) * (wb).z; a27 += (x2) * (wb).w;                              \
    a30 += (x3) * (wa).x; a31 += (x3) * (wa).y;                              \
    a32 += (x3) * (wa).z; a33 += (x3) * (wa).w;                              \
    a34 += (x3) * (wb).x; a35 += (x3) * (wb).y;                              \
    a36 += (x3) * (wb).z; a37 += (x3) * (wb).w;

// GEMM: 4 rows x 8 cols per thread (R1-R10: correctness-proven).  All named
// scalars.  unroll 2 under the 128-VGPR cap of (256,4).
__global__ __launch_bounds__(256, 4)
void gemm64_scaled_kernel(const float* __restrict__ X, const float* __restrict__ W,
                          const float* __restrict__ dis,
                          __hip_bfloat16* __restrict__ Y, int n) {
    __shared__ float Ws[CH * CH];
    {
        float4* w4 = (float4*)Ws;
        const float4* g4 = (const float4*)W;
        for (int i = threadIdx.x; i < CH * CH / 4; i += 256) w4[i] = g4[i];
    }
    __syncthreads();
    int t = threadIdx.x;
    int cbase = (t & 7) * 8;
    int r0 = blockIdx.x * 128 + (t >> 3) * 4;
    if (r0 >= n) return;
    int rB = min(r0 + 1, n - 1);
    int rC = min(r0 + 2, n - 1);
    int rD = min(r0 + 3, n - 1);
    const float4* pA = (const float4*)(X + (size_t)r0 * CH);
    const float4* pB = (const float4*)(X + (size_t)rB * CH);
    const float4* pC = (const float4*)(X + (size_t)rC * CH);
    const float4* pD = (const float4*)(X + (size_t)rD * CH);

    float a00 = 0.f, a01 = 0.f, a02 = 0.f, a03 = 0.f;
    float a04 = 0.f, a05 = 0.f, a06 = 0.f, a07 = 0.f;
    float a10 = 0.f, a11 = 0.f, a12 = 0.f, a13 = 0.f;
    float a14 = 0.f, a15 = 0.f, a16 = 0.f, a17 = 0.f;
    float a20 = 0.f, a21 = 0.f, a22 = 0.f, a23 = 0.f;
    float a24 = 0.f, a25 = 0.f, a26 = 0.f, a27 = 0.f;
    float a30 = 0.f, a31 = 0.f, a32 = 0.f, a33 = 0.f;
    float a34 = 0.f, a35 = 0.f, a36 = 0.f, a37 = 0.f;

#pragma unroll 2
    for (int k4 = 0; k4 < CH / 4; ++k4) {
        float4 xa = pA[k4];
        float4 xb = pB[k4];
        float4 xc = pC[k4];
        float4 xd = pD[k4];
        const float* wr = &Ws[(k4 * 4) * CH + cbase];
        float4 wa, wb;
        wa = *(const float4*)(wr);
        wb = *(const float4*)(wr + 4);
        FMA32(xa.x, xb.x, xc.x, xd.x, wa, wb)
        wa = *(const float4*)(wr + CH);
        wb = *(const float4*)(wr + CH + 4);
        FMA32(xa.y, xb.y, xc.y, xd.y, wa, wb)
        wa = *(const float4*)(wr + 2 * CH);
        wb = *(const float4*)(wr + 2 * CH + 4);
        FMA32(xa.z, xb.z, xc.z, xd.z, wa, wb)
        wa = *(const float4*)(wr + 3 * CH);
        wb = *(const float4*)(wr + 3 * CH + 4);
        FMA32(xa.w, xb.w, xc.w, xd.w, wa, wb)
    }

    uint4 pk;
    float d0 = dis[r0];
    pk.x = pack_bf2(a00 * d0, a01 * d0);
    pk.y = pack_bf2(a02 * d0, a03 * d0);
    pk.z = pack_bf2(a04 * d0, a05 * d0);
    pk.w = pack_bf2(a06 * d0, a07 * d0);
    *(uint4*)(Y + (size_t)r0 * CH + cbase) = pk;
    if (r0 + 1 < n) {
        float d1 = dis[r0 + 1];
        pk.x = pack_bf2(a10 * d1, a11 * d1);
        pk.y = pack_bf2(a12 * d1, a13 * d1);
        pk.z = pack_bf2(a14 * d1, a15 * d1);
        pk.w = pack_bf2(a16 * d1, a17 * d1);
        *(uint4*)(Y + (size_t)(r0 + 1) * CH + cbase) = pk;
    }
    if (r0 + 2 < n) {
        float d2 = dis[r0 + 2];
        pk.x = pack_bf2(a20 * d2, a21 * d2);
        pk.y = pack_bf2(a22 * d2, a23 * d2);
        pk.z = pack_bf2(a24 * d2, a25 * d2);
        pk.w = pack_bf2(a26 * d2, a27 * d2);
        *(uint4*)(Y + (size_t)(r0 + 2) * CH + cbase) = pk;
    }
    if (r0 + 3 < n) {
        float d3 = dis[r0 + 3];
        pk.x = pack_bf2(a30 * d3, a31 * d3);
        pk.y = pack_bf2(a32 * d3, a33 * d3);
        pk.z = pack_bf2(a34 * d3, a35 * d3);
        pk.w = pack_bf2(a36 * d3, a37 * d3);
        *(uint4*)(Y + (size_t)(r0 + 3) * CH + cbase) = pk;
    }
}

// R11 gather body: R7's exact load count (16-batch unmasked, 8 loads) +
// ONE-round tail.  Remainder r = cnt mod 16: r>8 -> one masked-16 round
// (8 loads, was 2 serial masked-8 rounds in R7); 0<r<=8 -> one masked-8
// round (4 loads, identical to R7).  Branch is wave-uniform (cnt uniform).
// Masking exact: shfl idx clamped to c1m, invalid slots zeroed (bf_lo(0)=0).
#define GATHER_SHFL_BODY(XWS)                                                 \
    const unsigned* XWSP = (XWS);                                             \
    int beg = rs[wid];                                                        \
    int end = rs[wid + 1];                                                    \
    unsigned cp4 = (unsigned)cp << 2;                                         \
    float accx = 0.f, accy = 0.f;                                             \
    for (int base = beg; base < end; base += 64) {                            \
        int cnt = min(64, end - base);                                        \
        int myColB = (base + lane < end) ? (col[base + lane] << 7) : 0;       \
        int eb = 0;                                                           \
        for (; eb + 16 <= cnt; eb += 16) {                                    \
            unsigned o0 = (unsigned)__shfl(myColB, eb + half, 64) | cp4;      \
            unsigned o1 = (unsigned)__shfl(myColB, eb + 2 + half, 64) | cp4;  \
            unsigned o2 = (unsigned)__shfl(myColB, eb + 4 + half, 64) | cp4;  \
            unsigned o3 = (unsigned)__shfl(myColB, eb + 6 + half, 64) | cp4;  \
            unsigned o4 = (unsigned)__shfl(myColB, eb + 8 + half, 64) | cp4;  \
            unsigned o5 = (unsigned)__shfl(myColB, eb + 10 + half, 64) | cp4; \
            unsigned o6 = (unsigned)__shfl(myColB, eb + 12 + half, 64) | cp4; \
            unsigned o7 = (unsigned)__shfl(myColB, eb + 14 + half, 64) | cp4; \
            unsigned u0 = ldu(XWSP, o0);                                      \
            unsigned u1 = ldu(XWSP, o1);                                      \
            unsigned u2 = ldu(XWSP, o2);                                      \
            unsigned u3 = ldu(XWSP, o3);                                      \
            unsigned u4 = ldu(XWSP, o4);                                      \
            unsigned u5 = ldu(XWSP, o5);                                      \
            unsigned u6 = ldu(XWSP, o6);                                      \
            unsigned u7 = ldu(XWSP, o7);                                      \
            accx += bf_lo(u0) + bf_lo(u1) + bf_lo(u2) + bf_lo(u3);            \
            accy += bf_hi(u0) + bf_hi(u1) + bf_hi(u2) + bf_hi(u3);            \
            accx += bf_lo(u4) + bf_lo(u5) + bf_lo(u6) + bf_lo(u7);            \
            accy += bf_hi(u4) + bf_hi(u5) + bf_hi(u6) + bf_hi(u7);            \
        }                                                                     \
        int r = cnt - eb;                                                     \
        int c1m = cnt - 1;                                                    \
        if (r > 8) {  /* one masked-16 round: 8 loads (same as R7's 2x4) */   \
            int i0 = eb + half;        int i1 = eb + 2 + half;                \
            int i2 = eb + 4 + half;    int i3 = eb + 6 + half;                \
            int i4 = eb + 8 + half;    int i5 = eb + 10 + half;               \
            int i6 = eb + 12 + half;   int i7 = eb + 14 + half;               \
            unsigned o0 = (unsigned)__shfl(myColB, min(i0, c1m), 64) | cp4;   \
            unsigned o1 = (unsigned)__shfl(myColB, min(i1, c1m), 64) | cp4;   \
            unsigned o2 = (unsigned)__shfl(myColB, min(i2, c1m), 64) | cp4;   \
            unsigned o3 = (unsigned)__shfl(myColB, min(i3, c1m), 64) | cp4;   \
            unsigned o4 = (unsigned)__shfl(myColB, min(i4, c1m), 64) | cp4;   \
            unsigned o5 = (unsigned)__shfl(myColB, min(i5, c1m), 64) | cp4;   \
            unsigned o6 = (unsigned)__shfl(myColB, min(i6, c1m), 64) | cp4;   \
            unsigned o7 = (unsigned)__shfl(myColB, min(i7, c1m), 64) | cp4;   \
            unsigned u0 = ldu(XWSP, o0);                                      \
            unsigned u1 = ldu(XWSP, o1);                                      \
            unsigned u2 = ldu(XWSP, o2);                                      \
            unsigned u3 = ldu(XWSP, o3);                                      \
            unsigned u4 = ldu(XWSP, o4);                                      \
            unsigned u5 = ldu(XWSP, o5);                                      \
            unsigned u6 = ldu(XWSP, o6);                                      \
            unsigned u7 = ldu(XWSP, o7);                                      \
            u0 = (i0 < cnt) ? u0 : 0u;  u1 = (i1 < cnt) ? u1 : 0u;            \
            u2 = (i2 < cnt) ? u2 : 0u;  u3 = (i3 < cnt) ? u3 : 0u;            \
            u4 = (i4 < cnt) ? u4 : 0u;  u5 = (i5 < cnt) ? u5 : 0u;            \
            u6 = (i6 < cnt) ? u6 : 0u;  u7 = (i7 < cnt) ? u7 : 0u;            \
            accx += bf_lo(u0) + bf_lo(u1) + bf_lo(u2) + bf_lo(u3);            \
            accy += bf_hi(u0) + bf_hi(u1) + bf_hi(u2) + bf_hi(u3);            \
            accx += bf_lo(u4) + bf_lo(u5) + bf_lo(u6) + bf_lo(u7);            \
            accy += bf_hi(u4) + bf_hi(u5) + bf_hi(u6) + bf_hi(u7);            \
        } else if (r > 0) {  /* one masked-8 round: 4 loads (R7 shape) */     \
            int i0 = eb + half;        int i1 = eb + 2 + half;                \
            int i2 = eb + 4 + half;    int i3 = eb + 6 + half;                \
            unsigned o0 = (unsigned)__shfl(myColB, min(i0, c1m), 64) | cp4;   \
            unsigned o1 = (unsigned)__shfl(myColB, min(i1, c1m), 64) | cp4;   \
            unsigned o2 = (unsigned)__shfl(myColB, min(i2, c1m), 64) | cp4;   \
            unsigned o3 = (unsigned)__shfl(myColB, min(i3, c1m), 64) | cp4;   \
            unsigned u0 = ldu(XWSP, o0);                                      \
            unsigned u1 = ldu(XWSP, o1);                                      \
            unsigned u2 = ldu(XWSP, o2);                                      \
            unsigned u3 = ldu(XWSP, o3);                                      \
            u0 = (i0 < cnt) ? u0 : 0u;  u1 = (i1 < cnt) ? u1 : 0u;            \
            u2 = (i2 < cnt) ? u2 : 0u;  u3 = (i3 < cnt) ? u3 : 0u;            \
            accx += bf_lo(u0) + bf_lo(u1) + bf_lo(u2) + bf_lo(u3);            \
            accy += bf_hi(u0) + bf_hi(u1) + bf_hi(u2) + bf_hi(u3);            \
        }                                                                     \
    }                                                                         \
    accx += __shfl_xor(accx, 32, 64);                                         \
    accy += __shfl_xor(accy, 32, 64);

// Layer-1 gather: h[wid, 2cp]=vx, h[wid, 2cp+1]=vy (fp32, dense float2/lane).
// One node per wave (max TLP).  Self-term us/dd/bias hoisted BEFORE the edge
// loop so their latency overlaps it (R5, proven).
__global__ __launch_bounds__(256)
void gather_pair_kernel(const unsigned* __restrict__ xws, const int* __restrict__ col,
                        const int* __restrict__ rs, const float* __restrict__ dis,
                        const float* __restrict__ b1, float* __restrict__ h,
                        int n, int E) {
    int wid = blockIdx.x * 4 + (threadIdx.x >> 6);
    int lane = threadIdx.x & 63;
    int cp = lane & 31;
    int half = lane >> 5;
    if (wid >= n) return;

    unsigned us = xws[(size_t)wid * 32 + cp];   // hoisted: overlaps gather
    float dd = dis[wid];
    float2 bb = ((const float2*)b1)[cp];

    GATHER_SHFL_BODY(xws)

    if (half == 0) {
        float2 o;
        o.x = fmaxf(dd * (accx + bf_lo(us)) + bb.x, 0.f);
        o.y = fmaxf(dd * (accy + bf_hi(us)) + bb.y, 0.f);
        ((float2*)h)[(size_t)wid * 32 + cp] = o;  // 8B/lane, dense 256B
    }
}

// Layer-2 gather + relu + per-block LN partials (NON-atomic per-block stores
// + 1-block reduce — R1/R2 lesson).
__global__ __launch_bounds__(256)
void gather_stats_kernel(const unsigned* __restrict__ xws, const int* __restrict__ col,
                         const int* __restrict__ rs, const float* __restrict__ dis,
                         const float* __restrict__ b2, float* __restrict__ out,
                         int n, int E, float* __restrict__ sums, float* __restrict__ sqs) {
    int wid = blockIdx.x * 4 + (threadIdx.x >> 6);
    int lane = threadIdx.x & 63;
    int cp = lane & 31;
    int half = lane >> 5;
    float vx = 0.f, vy = 0.f;
    if (wid < n) {
        unsigned us = xws[(size_t)wid * 32 + cp];   // hoisted
        float dd = dis[wid];
        float2 bb = ((const float2*)b2)[cp];
        GATHER_SHFL_BODY(xws)
        vx = fmaxf(dd * (accx + bf_lo(us)) + bb.x, 0.f);
        vy = fmaxf(dd * (accy + bf_hi(us)) + bb.y, 0.f);
        if (half == 0) {
            float2 o; o.x = vx; o.y = vy;
            ((float2*)out)[(size_t)wid * 32 + cp] = o;
        }
    }
    float s = (half == 0) ? vx + vy : 0.f;
    float sq = (half == 0) ? vx * vx + vy * vy : 0.f;
#pragma unroll
    for (int off = 32; off > 0; off >>= 1) {
        s += __shfl_down(s, off, 64);
        sq += __shfl_down(sq, off, 64);
    }
    __shared__ float ls[4], lq[4];
    int w = threadIdx.x >> 6;
    if ((threadIdx.x & 63) == 0) { ls[w] = s; lq[w] = sq; }
    __syncthreads();
    if (threadIdx.x == 0) {
        sums[blockIdx.x] = ls[0] + ls[1] + ls[2] + ls[3];
        sqs[blockIdx.x] = lq[0] + lq[1] + lq[2] + lq[3];
    }
}

__global__ void reduce_final_kernel(const float* __restrict__ sums, const float* __restrict__ sqs,
                                    int nb, float n_total, const float* __restrict__ lnw,
                                    const float* __restrict__ lnb, float* __restrict__ so) {
    float s = 0.0f, sq = 0.0f;
    for (int i = threadIdx.x; i < nb; i += 1024) { s += sums[i]; sq += sqs[i]; }
#pragma unroll
    for (int off = 32; off > 0; off >>= 1) {
        s += __shfl_down(s, off, 64);
        sq += __shfl_down(sq, off, 64);
    }
    __shared__ float ls[16], lq[16];
    int w = threadIdx.x >> 6;
    if ((threadIdx.x & 63) == 0) { ls[w] = s; lq[w] = sq; }
    __syncthreads();
    if (threadIdx.x == 0) {
        float ts = 0.0f, tq = 0.0f;
        for (int i = 0; i < 16; ++i) { ts += ls[i]; tq += lq[i]; }
        float mean = ts / n_total;
        float var = tq / n_total - mean * mean;
        float scale = rsqrtf(var + 1e-5f) * lnw[0];
        so[0] = scale;
        so[1] = lnb[0] - mean * scale;
    }
}

// 32B/thread (2x float4): halves block count vs 16B/thread.
__global__ void norm_kernel(float* __restrict__ x, int n8, const float* __restrict__ so) {
    int i = blockIdx.x * blockDim.x + threadIdx.x;
    if (i >= n8) return;
    float scale = so[0], off = so[1];
    float4* x4 = (float4*)x;
    float4 a = x4[2 * i];
    float4 b = x4[2 * i + 1];
    a.x = a.x * scale + off; a.y = a.y * scale + off;
    a.z = a.z * scale + off; a.w = a.w * scale + off;
    b.x = b.x * scale + off; b.y = b.y * scale + off;
    b.z = b.z * scale + off; b.w = b.w * scale + off;
    x4[2 * i] = a;
    x4[2 * i + 1] = b;
}

extern "C" void kernel_launch(void* const* d_in, const int* in_sizes, int n_in,
                              void* d_out, int out_size, void* d_ws, size_t ws_size,
                              hipStream_t stream) {
    const float* X   = (const float*)d_in[0];
    const int*   edg = (const int*)d_in[1];   // [2,E]: src row then dst row
    const float* W1  = (const float*)d_in[2];
    const float* b1  = (const float*)d_in[3];
    const float* W2  = (const float*)d_in[4];
    const float* b2  = (const float*)d_in[5];
    const float* lnw = (const float*)d_in[6];
    const float* lnb = (const float*)d_in[7];
    float* out = (float*)d_out;

    const int N  = in_sizes[0] / CH;   // 100000
    const int E  = in_sizes[1] / 2;    // 1600000
    const int NC = N * CH;             // 6.4M
    const int nNodeBlk = (N + 3) / 4;  // 25000 (4 nodes / block)
    const int nb = (N + 511) >> BSH;   // 196 buckets
    const int nblkE = (E + CHUNK - 1) / CHUNK;  // 98 edge-chunk blocks
    const int nvblk = nblkE * NREP;    // 392 virtual hist blocks

    const int* srcp = edg;
    const int* dstp = edg + E;

    // workspace layout (4B units).  pairs (E unsigned) dead after bucket_csr;
    // h (NC floats) overlays it.  rs is N+1 (rs[N]=E, branchless end).
    int*   col   = (int*)d_ws;                          // E
    int*   rs    = col + E;                             // N+1
    float* dis   = (float*)(rs + N + 1);                // N
    __hip_bfloat16* xws1 = (__hip_bfloat16*)(dis + N);  // NC bf16
    __hip_bfloat16* xws2 = xws1 + NC;                   // NC bf16
    float* h     = (float*)(xws2 + NC);                 // NC floats
    unsigned* pairs = (unsigned*)h;                     // E u32 (dead before h live)
    int*   bHist = (int*)(h + NC);                      // nvblk*nb
    int*   bStart= bHist + nvblk * nb;                  // nb+1
    float* sums  = (float*)(bStart + nb + 1);           // nNodeBlk
    float* sqs   = sums + nNodeBlk;                     // nNodeBlk
    float* so    = sqs + nNodeBlk;                      // 2 {scale, offset}

    const int B = 256;
    const int nGemmBlk = (N + 127) / 128;               // 782 (4 rows/thread)

    // ---- CSR build (no global atomics, no memset) ----
    coarse_hist_kernel<<<nblkE, 1024, 0, stream>>>(dstp, bHist, E, nb);
    scan_hist_kernel<<<1, 1024, 0, stream>>>(bHist, bStart, nvblk, nb);
    scatter_pairs_kernel<<<nblkE, 1024, 0, stream>>>(srcp, dstp, bHist, pairs, E, nb);
    bucket_csr_kernel<<<nb, 1024, 0, stream>>>(pairs, bStart, col, rs, dis, N, nb, E);
    // rs = row_start; row i spans [rs[i], rs[i+1]); rs[N] = E

    // ---- layer 1 ----
    gemm64_scaled_kernel<<<nGemmBlk, B, 0, stream>>>(X, W1, dis, xws1, N);
    gather_pair_kernel<<<nNodeBlk, B, 0, stream>>>((const unsigned*)xws1, col, rs, dis,
                                                   b1, h, N, E);

    // ---- layer 2 ----
    gemm64_scaled_kernel<<<nGemmBlk, B, 0, stream>>>(h, W2, dis, xws2, N);
    gather_stats_kernel<<<nNodeBlk, B, 0, stream>>>((const unsigned*)xws2, col, rs, dis,
                                                    b2, out, N, E, sums, sqs);

    // ---- graph layernorm ----
    reduce_final_kernel<<<1, 1024, 0, stream>>>(sums, sqs, nNodeBlk, (float)NC, lnw, lnb, so);
    norm_kernel<<<(NC / 8 + B - 1) / B, B, 0, stream>>>(out, NC / 8, so);
}

// Round 12
// 265.464 us; speedup vs baseline: 1.1095x; 1.0938x over previous
//
#include <hip/hip_runtime.h>
#include <hip/hip_bf16.h>

#define CH 64          // IN_C = HID_C = OUT_C = 64
#define BSH 9          // bucket shift: 512 nodes/bucket
#define CHUNK 16384    // edges per block in hist/scatter passes (1024 thr x 16)
#define MAXB 10240     // LDS col buffer (edges/bucket ~8163 +- 90)
#define NREP 4         // LDS histogram replicas (quarter-block each)
#define RPAD 257       // replica stride: 257 ints rotates bank mapping
// pairs packing: src < 2^17 (N=100000 <= 131072), dstLocal < 2^9 -> 26 bits
//
// SESSION LEDGER (hard-won):
//  R1/R2: 25k global atomicAdds to ONE cache line serialize cross-XCD = +276us.
//  R4:    in-wave GEMM via shfl+LDS = +96 DS ops/node: DS-pipe chains poison.
//  R7:    masked-tail single-round: serial load-rounds are the gather lever
//         when load count is constant (48.7->43.3us).
//  R8/R9: 4x hist replication helps coarse/scatter; scan must be chain-free.
//  R10/R11: FETCH 88->157MB was NOT the masked-32's extra loads alone — the
//         rs N->N+1 growth shifted xws1 by 4B off 128B alignment, so EVERY
//         gathered row straddled two cache lines.  R11 (R7-equal loads)
//         kept FETCH at 157MB, proving alignment was the driver.  RULE:
//         any workspace layout change must re-verify 128B alignment of
//         row-granular buffers.
//  R12:   this round — pad rs to N+32 words (all downstream buffers re-align;
//         E, N are multiples of 32).  Keep R11 one-round tail + scan-16.
//  prev:  scalar s_load of col regressed; serial nodes/wave regressed 2.3x.

// ---------- CSR build: two-level counting sort, all atomics in LDS ----------

__global__ __launch_bounds__(1024)
void coarse_hist_kernel(const int* __restrict__ dst, int* __restrict__ blockHist,
                        int E, int nb) {
    __shared__ int h[NREP * RPAD];
    int t = threadIdx.x;
    int rep = t >> 8;
    for (int i = t; i < NREP * RPAD; i += 1024) h[i] = 0;
    __syncthreads();
    int* hr = h + rep * RPAD;
    int base = blockIdx.x * CHUNK + t * 16;
#pragma unroll
    for (int j = 0; j < 16; j += 4) {
        int e = base + j;
        if (e + 3 < E) {
            int4 d = *(const int4*)(dst + e);
            atomicAdd(&hr[d.x >> BSH], 1);
            atomicAdd(&hr[d.y >> BSH], 1);
            atomicAdd(&hr[d.z >> BSH], 1);
            atomicAdd(&hr[d.w >> BSH], 1);
        } else {
            for (int k = e; k < E && k < e + 4; ++k) atomicAdd(&hr[dst[k] >> BSH], 1);
        }
    }
    __syncthreads();
    for (int r = 0; r < NREP; ++r)
        for (int i = t; i < nb; i += 1024)
            blockHist[(blockIdx.x * NREP + r) * nb + i] = h[r * RPAD + i];
}

// 4 groups x 256 threads; group g owns vblk quarter [q0,q1); 16-wide batches.
__global__ __launch_bounds__(1024)
void scan_hist_kernel(int* __restrict__ blockHist, int* __restrict__ bucketStart,
                      int nblk, int nb) {
    __shared__ int qsum[NREP][256];
    __shared__ int tots[256];
    __shared__ int offs[256];
    int t = threadIdx.x;
    int g = t >> 8;        // quarter index 0..3
    int b = t & 255;       // bucket index
    int qlen = nblk / NREP;
    int q0 = g * qlen;
    int q1 = (g == NREP - 1) ? nblk : q0 + qlen;
    int s = 0;
    if (b < nb) {
        int blk = q0;
        for (; blk + 16 <= q1; blk += 16) {
            int v0 = blockHist[(blk + 0) * nb + b];
            int v1 = blockHist[(blk + 1) * nb + b];
            int v2 = blockHist[(blk + 2) * nb + b];
            int v3 = blockHist[(blk + 3) * nb + b];
            int v4 = blockHist[(blk + 4) * nb + b];
            int v5 = blockHist[(blk + 5) * nb + b];
            int v6 = blockHist[(blk + 6) * nb + b];
            int v7 = blockHist[(blk + 7) * nb + b];
            int v8 = blockHist[(blk + 8) * nb + b];
            int v9 = blockHist[(blk + 9) * nb + b];
            int va = blockHist[(blk + 10) * nb + b];
            int vb = blockHist[(blk + 11) * nb + b];
            int vc = blockHist[(blk + 12) * nb + b];
            int vd = blockHist[(blk + 13) * nb + b];
            int ve = blockHist[(blk + 14) * nb + b];
            int vf = blockHist[(blk + 15) * nb + b];
            s += v0 + v1 + v2 + v3 + v4 + v5 + v6 + v7
               + v8 + v9 + va + vb + vc + vd + ve + vf;
        }
        for (; blk < q1; ++blk) s += blockHist[blk * nb + b];
    }
    qsum[g][b] = s;
    __syncthreads();
    if (t < 256) {
        tots[t] = qsum[0][t] + qsum[1][t] + qsum[2][t] + qsum[3][t];
        offs[t] = tots[t];
    }
    __syncthreads();
    for (int off = 1; off < 256; off <<= 1) {
        int a = (t < 256 && t >= off) ? offs[t - off] : 0;
        __syncthreads();
        if (t < 256) offs[t] += a;
        __syncthreads();
    }
    // offs = inclusive scan of tots; exclusive = offs[b]-tots[b].
    if (b < nb) {
        int r = offs[b] - tots[b];
        for (int gg = 0; gg < g; ++gg) r += qsum[gg][b];
        int blk = q0;
        for (; blk + 16 <= q1; blk += 16) {
            int v0 = blockHist[(blk + 0) * nb + b];
            int v1 = blockHist[(blk + 1) * nb + b];
            int v2 = blockHist[(blk + 2) * nb + b];
            int v3 = blockHist[(blk + 3) * nb + b];
            int v4 = blockHist[(blk + 4) * nb + b];
            int v5 = blockHist[(blk + 5) * nb + b];
            int v6 = blockHist[(blk + 6) * nb + b];
            int v7 = blockHist[(blk + 7) * nb + b];
            int v8 = blockHist[(blk + 8) * nb + b];
            int v9 = blockHist[(blk + 9) * nb + b];
            int va = blockHist[(blk + 10) * nb + b];
            int vb = blockHist[(blk + 11) * nb + b];
            int vc = blockHist[(blk + 12) * nb + b];
            int vd = blockHist[(blk + 13) * nb + b];
            int ve = blockHist[(blk + 14) * nb + b];
            int vf = blockHist[(blk + 15) * nb + b];
            blockHist[(blk + 0) * nb + b] = r; r += v0;
            blockHist[(blk + 1) * nb + b] = r; r += v1;
            blockHist[(blk + 2) * nb + b] = r; r += v2;
            blockHist[(blk + 3) * nb + b] = r; r += v3;
            blockHist[(blk + 4) * nb + b] = r; r += v4;
            blockHist[(blk + 5) * nb + b] = r; r += v5;
            blockHist[(blk + 6) * nb + b] = r; r += v6;
            blockHist[(blk + 7) * nb + b] = r; r += v7;
            blockHist[(blk + 8) * nb + b] = r; r += v8;
            blockHist[(blk + 9) * nb + b] = r; r += v9;
            blockHist[(blk + 10) * nb + b] = r; r += va;
            blockHist[(blk + 11) * nb + b] = r; r += vb;
            blockHist[(blk + 12) * nb + b] = r; r += vc;
            blockHist[(blk + 13) * nb + b] = r; r += vd;
            blockHist[(blk + 14) * nb + b] = r; r += ve;
            blockHist[(blk + 15) * nb + b] = r; r += vf;
        }
        for (; blk < q1; ++blk) {
            int v = blockHist[blk * nb + b];
            blockHist[blk * nb + b] = r;
            r += v;
        }
    }
    if (t <= nb) bucketStart[t] = offs[t] - tots[t];  // tots[t]=0 for t>=nb
}

// pairs entry: (dstLocal << 17) | src.  Per-replica cursors (disjoint base
// ranges from the virtual-block scan) — within-bucket order is irrelevant.
__global__ __launch_bounds__(1024)
void scatter_pairs_kernel(const int* __restrict__ src, const int* __restrict__ dst,
                          const int* __restrict__ blockBase, unsigned* __restrict__ pairs,
                          int E, int nb) {
    __shared__ int cur[NREP * RPAD];
    int t = threadIdx.x;
    int rep = t >> 8;
    for (int r = 0; r < NREP; ++r)
        for (int i = t; i < nb; i += 1024)
            cur[r * RPAD + i] = blockBase[(blockIdx.x * NREP + r) * nb + i];
    __syncthreads();
    int* cr = cur + rep * RPAD;
    int base = blockIdx.x * CHUNK + t * 16;
#pragma unroll
    for (int j = 0; j < 16; j += 4) {
        int e = base + j;
        if (e + 3 < E) {
            int4 d = *(const int4*)(dst + e);
            int4 s = *(const int4*)(src + e);
            int p0 = atomicAdd(&cr[d.x >> BSH], 1);
            pairs[p0] = ((unsigned)(d.x & 511) << 17) | (unsigned)s.x;
            int p1 = atomicAdd(&cr[d.y >> BSH], 1);
            pairs[p1] = ((unsigned)(d.y & 511) << 17) | (unsigned)s.y;
            int p2 = atomicAdd(&cr[d.z >> BSH], 1);
            pairs[p2] = ((unsigned)(d.z & 511) << 17) | (unsigned)s.z;
            int p3 = atomicAdd(&cr[d.w >> BSH], 1);
            pairs[p3] = ((unsigned)(d.w & 511) << 17) | (unsigned)s.w;
        } else {
            for (int k = e; k < E && k < e + 4; ++k) {
                int d = dst[k];
                int p = atomicAdd(&cr[d >> BSH], 1);
                pairs[p] = ((unsigned)(d & 511) << 17) | (unsigned)src[k];
            }
        }
    }
}

__global__ __launch_bounds__(1024)
void bucket_csr_kernel(const unsigned* __restrict__ pairs, const int* __restrict__ bucketStart,
                       int* __restrict__ col, int* __restrict__ rs, float* __restrict__ dis,
                       int N, int nb, int E) {
    __shared__ int hist[512];
    __shared__ int offs[512];
    __shared__ int cursor[512];
    __shared__ int lcol[MAXB];
    int b = blockIdx.x;
    int t = threadIdx.x;
    int n0 = b << BSH;
    int nn = min(512, N - n0);
    int start = bucketStart[b];
    int endp = bucketStart[b + 1];
    int cnt = endp - start;
    bool big = cnt > MAXB;  // safety fallback: direct (uncoalesced) col writes
    for (int i = t; i < nn; i += 1024) hist[i] = 0;
    __syncthreads();
    for (int i = start + t; i < endp; i += 1024) {
        unsigned p = pairs[i];
        atomicAdd(&hist[p >> 17], 1);
    }
    __syncthreads();
    if (t < 512) offs[t] = (t < nn) ? hist[t] : 0;
    __syncthreads();
    for (int off = 1; off < 512; off <<= 1) {
        int a = (t < 512 && t >= off) ? offs[t - off] : 0;
        __syncthreads();
        if (t < 512) offs[t] += a;
        __syncthreads();
    }
    if (t < nn) {
        int excl = offs[t] - hist[t];          // exclusive scan value
        rs[n0 + t] = start + excl;
        dis[n0 + t] = rsqrtf((float)hist[t] + 1.0f);
        cursor[t] = excl;
    }
    if (b == 0 && t == 0) rs[N] = E;           // branchless gather end
    __syncthreads();
    for (int i = start + t; i < endp; i += 1024) {
        unsigned p = pairs[i];
        int pos = atomicAdd(&cursor[p >> 17], 1);
        int sv = (int)(p & 0x1FFFFu);
        if (big) col[start + pos] = sv;
        else lcol[pos] = sv;
    }
    __syncthreads();
    if (!big) {
        for (int i = t; i < cnt; i += 1024) col[start + i] = lcol[i];
    }
}

// ---------- compute ----------

__device__ inline unsigned pack_bf2(float a, float b) {
    __hip_bfloat162 t;
    t.x = __float2bfloat16(a);
    t.y = __float2bfloat16(b);
    unsigned u;
    __builtin_memcpy(&u, &t, 4);
    return u;
}

__device__ inline float bf_lo(unsigned u) {
    unsigned w = u << 16; float f; __builtin_memcpy(&f, &w, 4); return f;
}
__device__ inline float bf_hi(unsigned u) {
    unsigned w = u & 0xffff0000u; float f; __builtin_memcpy(&f, &w, 4); return f;
}

// uniform-base + 32-bit byte-offset load -> global_load_dword v, voff, s[base]
__device__ inline unsigned ldu(const unsigned* p, unsigned boff) {
    return *(const unsigned*)((const char*)p + boff);
}

#define FMA32(x0, x1, x2, x3, wa, wb)                                        \
    a00 += (x0) * (wa).x; a01 += (x0) * (wa).y;                              \
    a02 += (x0) * (wa).z; a03 += (x0) * (wa).w;                              \
    a04 += (x0) * (wb).x; a05 += (x0) * (wb).y;                              \
    a06 += (x0) * (wb).z; a07 += (x0) * (wb).w;                              \
    a10 += (x1) * (wa).x; a11 += (x1) * (wa).y;                              \
    a12 += (x1) * (wa).z; a13 += (x1) * (wa).w;                              \
    a14 += (x1) * (wb).x; a15 += (x1) * (wb).y;                              \
    a16 += (x1) * (wb).z; a17 += (x1) * (wb).w;                              \
    a20 += (x2) * (wa).x; a21 += (x2) * (wa).y;                              \
    a22 += (x2) * (wa).z; a23 += (x2) * (wa).w;                              \
    a24 += (x2) * (wb).x; a25 += (x2) * (wb).y;                              \
    a26 += (x2) * (wb).z; a27 += (x2) * (wb).w;                              \
    a30 += (x3) * (wa).x; a31 += (x3) * (wa).y;                              \
    a32 += (x3) * (wa).z; a33 += (x3) * (wa).w;                              \
    a34 += (x3) * (wb).x; a35 += (x3) * (wb).y;                              \
    a36 += (x3) * (wb).z; a37 += (x3) * (wb).w;

// GEMM: 4 rows x 8 cols per thread (R1-R11: correctness-proven).  All named
// scalars.  unroll 2 under the 128-VGPR cap of (256,4).
__global__ __launch_bounds__(256, 4)
void gemm64_scaled_kernel(const float* __restrict__ X, const float* __restrict__ W,
                          const float* __restrict__ dis,
                          __hip_bfloat16* __restrict__ Y, int n) {
    __shared__ float Ws[CH * CH];
    {
        float4* w4 = (float4*)Ws;
        const float4* g4 = (const float4*)W;
        for (int i = threadIdx.x; i < CH * CH / 4; i += 256) w4[i] = g4[i];
    }
    __syncthreads();
    int t = threadIdx.x;
    int cbase = (t & 7) * 8;
    int r0 = blockIdx.x * 128 + (t >> 3) * 4;
    if (r0 >= n) return;
    int rB = min(r0 + 1, n - 1);
    int rC = min(r0 + 2, n - 1);
    int rD = min(r0 + 3, n - 1);
    const float4* pA = (const float4*)(X + (size_t)r0 * CH);
    const float4* pB = (const float4*)(X + (size_t)rB * CH);
    const float4* pC = (const float4*)(X + (size_t)rC * CH);
    const float4* pD = (const float4*)(X + (size_t)rD * CH);

    float a00 = 0.f, a01 = 0.f, a02 = 0.f, a03 = 0.f;
    float a04 = 0.f, a05 = 0.f, a06 = 0.f, a07 = 0.f;
    float a10 = 0.f, a11 = 0.f, a12 = 0.f, a13 = 0.f;
    float a14 = 0.f, a15 = 0.f, a16 = 0.f, a17 = 0.f;
    float a20 = 0.f, a21 = 0.f, a22 = 0.f, a23 = 0.f;
    float a24 = 0.f, a25 = 0.f, a26 = 0.f, a27 = 0.f;
    float a30 = 0.f, a31 = 0.f, a32 = 0.f, a33 = 0.f;
    float a34 = 0.f, a35 = 0.f, a36 = 0.f, a37 = 0.f;

#pragma unroll 2
    for (int k4 = 0; k4 < CH / 4; ++k4) {
        float4 xa = pA[k4];
        float4 xb = pB[k4];
        float4 xc = pC[k4];
        float4 xd = pD[k4];
        const float* wr = &Ws[(k4 * 4) * CH + cbase];
        float4 wa, wb;
        wa = *(const float4*)(wr);
        wb = *(const float4*)(wr + 4);
        FMA32(xa.x, xb.x, xc.x, xd.x, wa, wb)
        wa = *(const float4*)(wr + CH);
        wb = *(const float4*)(wr + CH + 4);
        FMA32(xa.y, xb.y, xc.y, xd.y, wa, wb)
        wa = *(const float4*)(wr + 2 * CH);
        wb = *(const float4*)(wr + 2 * CH + 4);
        FMA32(xa.z, xb.z, xc.z, xd.z, wa, wb)
        wa = *(const float4*)(wr + 3 * CH);
        wb = *(const float4*)(wr + 3 * CH + 4);
        FMA32(xa.w, xb.w, xc.w, xd.w, wa, wb)
    }

    uint4 pk;
    float d0 = dis[r0];
    pk.x = pack_bf2(a00 * d0, a01 * d0);
    pk.y = pack_bf2(a02 * d0, a03 * d0);
    pk.z = pack_bf2(a04 * d0, a05 * d0);
    pk.w = pack_bf2(a06 * d0, a07 * d0);
    *(uint4*)(Y + (size_t)r0 * CH + cbase) = pk;
    if (r0 + 1 < n) {
        float d1 = dis[r0 + 1];
        pk.x = pack_bf2(a10 * d1, a11 * d1);
        pk.y = pack_bf2(a12 * d1, a13 * d1);
        pk.z = pack_bf2(a14 * d1, a15 * d1);
        pk.w = pack_bf2(a16 * d1, a17 * d1);
        *(uint4*)(Y + (size_t)(r0 + 1) * CH + cbase) = pk;
    }
    if (r0 + 2 < n) {
        float d2 = dis[r0 + 2];
        pk.x = pack_bf2(a20 * d2, a21 * d2);
        pk.y = pack_bf2(a22 * d2, a23 * d2);
        pk.z = pack_bf2(a24 * d2, a25 * d2);
        pk.w = pack_bf2(a26 * d2, a27 * d2);
        *(uint4*)(Y + (size_t)(r0 + 2) * CH + cbase) = pk;
    }
    if (r0 + 3 < n) {
        float d3 = dis[r0 + 3];
        pk.x = pack_bf2(a30 * d3, a31 * d3);
        pk.y = pack_bf2(a32 * d3, a33 * d3);
        pk.z = pack_bf2(a34 * d3, a35 * d3);
        pk.w = pack_bf2(a36 * d3, a37 * d3);
        *(uint4*)(Y + (size_t)(r0 + 3) * CH + cbase) = pk;
    }
}

// R11 gather body (kept): R7's exact load count + ONE-round tail.
// Remainder r = cnt mod 16: r>8 -> one masked-16 round (8 loads); 0<r<=8 ->
// one masked-8 round (4 loads).  Wave-uniform branch; clamped idx, invalid
// slots zeroed (exact: bf_lo(0)=0).
#define GATHER_SHFL_BODY(XWS)                                                 \
    const unsigned* XWSP = (XWS);                                             \
    int beg = rs[wid];                                                        \
    int end = rs[wid + 1];                                                    \
    unsigned cp4 = (unsigned)cp << 2;                                         \
    float accx = 0.f, accy = 0.f;                                             \
    for (int base = beg; base < end; base += 64) {                            \
        int cnt = min(64, end - base);                                        \
        int myColB = (base + lane < end) ? (col[base + lane] << 7) : 0;       \
        int eb = 0;                                                           \
        for (; eb + 16 <= cnt; eb += 16) {                                    \
            unsigned o0 = (unsigned)__shfl(myColB, eb + half, 64) | cp4;      \
            unsigned o1 = (unsigned)__shfl(myColB, eb + 2 + half, 64) | cp4;  \
            unsigned o2 = (unsigned)__shfl(myColB, eb + 4 + half, 64) | cp4;  \
            unsigned o3 = (unsigned)__shfl(myColB, eb + 6 + half, 64) | cp4;  \
            unsigned o4 = (unsigned)__shfl(myColB, eb + 8 + half, 64) | cp4;  \
            unsigned o5 = (unsigned)__shfl(myColB, eb + 10 + half, 64) | cp4; \
            unsigned o6 = (unsigned)__shfl(myColB, eb + 12 + half, 64) | cp4; \
            unsigned o7 = (unsigned)__shfl(myColB, eb + 14 + half, 64) | cp4; \
            unsigned u0 = ldu(XWSP, o0);                                      \
            unsigned u1 = ldu(XWSP, o1);                                      \
            unsigned u2 = ldu(XWSP, o2);                                      \
            unsigned u3 = ldu(XWSP, o3);                                      \
            unsigned u4 = ldu(XWSP, o4);                                      \
            unsigned u5 = ldu(XWSP, o5);                                      \
            unsigned u6 = ldu(XWSP, o6);                                      \
            unsigned u7 = ldu(XWSP, o7);                                      \
            accx += bf_lo(u0) + bf_lo(u1) + bf_lo(u2) + bf_lo(u3);            \
            accy += bf_hi(u0) + bf_hi(u1) + bf_hi(u2) + bf_hi(u3);            \
            accx += bf_lo(u4) + bf_lo(u5) + bf_lo(u6) + bf_lo(u7);            \
            accy += bf_hi(u4) + bf_hi(u5) + bf_hi(u6) + bf_hi(u7);            \
        }                                                                     \
        int r = cnt - eb;                                                     \
        int c1m = cnt - 1;                                                    \
        if (r > 8) {  /* one masked-16 round: 8 loads */                      \
            int i0 = eb + half;        int i1 = eb + 2 + half;                \
            int i2 = eb + 4 + half;    int i3 = eb + 6 + half;                \
            int i4 = eb + 8 + half;    int i5 = eb + 10 + half;               \
            int i6 = eb + 12 + half;   int i7 = eb + 14 + half;               \
            unsigned o0 = (unsigned)__shfl(myColB, min(i0, c1m), 64) | cp4;   \
            unsigned o1 = (unsigned)__shfl(myColB, min(i1, c1m), 64) | cp4;   \
            unsigned o2 = (unsigned)__shfl(myColB, min(i2, c1m), 64) | cp4;   \
            unsigned o3 = (unsigned)__shfl(myColB, min(i3, c1m), 64) | cp4;   \
            unsigned o4 = (unsigned)__shfl(myColB, min(i4, c1m), 64) | cp4;   \
            unsigned o5 = (unsigned)__shfl(myColB, min(i5, c1m), 64) | cp4;   \
            unsigned o6 = (unsigned)__shfl(myColB, min(i6, c1m), 64) | cp4;   \
            unsigned o7 = (unsigned)__shfl(myColB, min(i7, c1m), 64) | cp4;   \
            unsigned u0 = ldu(XWSP, o0);                                      \
            unsigned u1 = ldu(XWSP, o1);                                      \
            unsigned u2 = ldu(XWSP, o2);                                      \
            unsigned u3 = ldu(XWSP, o3);                                      \
            unsigned u4 = ldu(XWSP, o4);                                      \
            unsigned u5 = ldu(XWSP, o5);                                      \
            unsigned u6 = ldu(XWSP, o6);                                      \
            unsigned u7 = ldu(XWSP, o7);                                      \
            u0 = (i0 < cnt) ? u0 : 0u;  u1 = (i1 < cnt) ? u1 : 0u;            \
            u2 = (i2 < cnt) ? u2 : 0u;  u3 = (i3 < cnt) ? u3 : 0u;            \
            u4 = (i4 < cnt) ? u4 : 0u;  u5 = (i5 < cnt) ? u5 : 0u;            \
            u6 = (i6 < cnt) ? u6 : 0u;  u7 = (i7 < cnt) ? u7 : 0u;            \
            accx += bf_lo(u0) + bf_lo(u1) + bf_lo(u2) + bf_lo(u3);            \
            accy += bf_hi(u0) + bf_hi(u1) + bf_hi(u2) + bf_hi(u3);            \
            accx += bf_lo(u4) + bf_lo(u5) + bf_lo(u6) + bf_lo(u7);            \
            accy += bf_hi(u4) + bf_hi(u5) + bf_hi(u6) + bf_hi(u7);            \
        } else if (r > 0) {  /* one masked-8 round: 4 loads */                \
            int i0 = eb + half;        int i1 = eb + 2 + half;                \
            int i2 = eb + 4 + half;    int i3 = eb + 6 + half;                \
            unsigned o0 = (unsigned)__shfl(myColB, min(i0, c1m), 64) | cp4;   \
            unsigned o1 = (unsigned)__shfl(myColB, min(i1, c1m), 64) | cp4;   \
            unsigned o2 = (unsigned)__shfl(myColB, min(i2, c1m), 64) | cp4;   \
            unsigned o3 = (unsigned)__shfl(myColB, min(i3, c1m), 64) | cp4;   \
            unsigned u0 = ldu(XWSP, o0);                                      \
            unsigned u1 = ldu(XWSP, o1);                                      \
            unsigned u2 = ldu(XWSP, o2);                                      \
            unsigned u3 = ldu(XWSP, o3);                                      \
            u0 = (i0 < cnt) ? u0 : 0u;  u1 = (i1 < cnt) ? u1 : 0u;            \
            u2 = (i2 < cnt) ? u2 : 0u;  u3 = (i3 < cnt) ? u3 : 0u;            \
            accx += bf_lo(u0) + bf_lo(u1) + bf_lo(u2) + bf_lo(u3);            \
            accy += bf_hi(u0) + bf_hi(u1) + bf_hi(u2) + bf_hi(u3);            \
        }                                                                     \
    }                                                                         \
    accx += __shfl_xor(accx, 32, 64);                                         \
    accy += __shfl_xor(accy, 32, 64);

// Layer-1 gather: h[wid, 2cp]=vx, h[wid, 2cp+1]=vy (fp32, dense float2/lane).
// One node per wave (max TLP).  Self-term us/dd/bias hoisted BEFORE the edge
// loop so their latency overlaps it (R5, proven).
__global__ __launch_bounds__(256)
void gather_pair_kernel(const unsigned* __restrict__ xws, const int* __restrict__ col,
                        const int* __restrict__ rs, const float* __restrict__ dis,
                        const float* __restrict__ b1, float* __restrict__ h,
                        int n, int E) {
    int wid = blockIdx.x * 4 + (threadIdx.x >> 6);
    int lane = threadIdx.x & 63;
    int cp = lane & 31;
    int half = lane >> 5;
    if (wid >= n) return;

    unsigned us = xws[(size_t)wid * 32 + cp];   // hoisted: overlaps gather
    float dd = dis[wid];
    float2 bb = ((const float2*)b1)[cp];

    GATHER_SHFL_BODY(xws)

    if (half == 0) {
        float2 o;
        o.x = fmaxf(dd * (accx + bf_lo(us)) + bb.x, 0.f);
        o.y = fmaxf(dd * (accy + bf_hi(us)) + bb.y, 0.f);
        ((float2*)h)[(size_t)wid * 32 + cp] = o;  // 8B/lane, dense 256B
    }
}

// Layer-2 gather + relu + per-block LN partials (NON-atomic per-block stores
// + 1-block reduce — R1/R2 lesson).
__global__ __launch_bounds__(256)
void gather_stats_kernel(const unsigned* __restrict__ xws, const int* __restrict__ col,
                         const int* __restrict__ rs, const float* __restrict__ dis,
                         const float* __restrict__ b2, float* __restrict__ out,
                         int n, int E, float* __restrict__ sums, float* __restrict__ sqs) {
    int wid = blockIdx.x * 4 + (threadIdx.x >> 6);
    int lane = threadIdx.x & 63;
    int cp = lane & 31;
    int half = lane >> 5;
    float vx = 0.f, vy = 0.f;
    if (wid < n) {
        unsigned us = xws[(size_t)wid * 32 + cp];   // hoisted
        float dd = dis[wid];
        float2 bb = ((const float2*)b2)[cp];
        GATHER_SHFL_BODY(xws)
        vx = fmaxf(dd * (accx + bf_lo(us)) + bb.x, 0.f);
        vy = fmaxf(dd * (accy + bf_hi(us)) + bb.y, 0.f);
        if (half == 0) {
            float2 o; o.x = vx; o.y = vy;
            ((float2*)out)[(size_t)wid * 32 + cp] = o;
        }
    }
    float s = (half == 0) ? vx + vy : 0.f;
    float sq = (half == 0) ? vx * vx + vy * vy : 0.f;
#pragma unroll
    for (int off = 32; off > 0; off >>= 1) {
        s += __shfl_down(s, off, 64);
        sq += __shfl_down(sq, off, 64);
    }
    __shared__ float ls[4], lq[4];
    int w = threadIdx.x >> 6;
    if ((threadIdx.x & 63) == 0) { ls[w] = s; lq[w] = sq; }
    __syncthreads();
    if (threadIdx.x == 0) {
        sums[blockIdx.x] = ls[0] + ls[1] + ls[2] + ls[3];
        sqs[blockIdx.x] = lq[0] + lq[1] + lq[2] + lq[3];
    }
}

__global__ void reduce_final_kernel(const float* __restrict__ sums, const float* __restrict__ sqs,
                                    int nb, float n_total, const float* __restrict__ lnw,
                                    const float* __restrict__ lnb, float* __restrict__ so) {
    float s = 0.0f, sq = 0.0f;
    for (int i = threadIdx.x; i < nb; i += 1024) { s += sums[i]; sq += sqs[i]; }
#pragma unroll
    for (int off = 32; off > 0; off >>= 1) {
        s += __shfl_down(s, off, 64);
        sq += __shfl_down(sq, off, 64);
    }
    __shared__ float ls[16], lq[16];
    int w = threadIdx.x >> 6;
    if ((threadIdx.x & 63) == 0) { ls[w] = s; lq[w] = sq; }
    __syncthreads();
    if (threadIdx.x == 0) {
        float ts = 0.0f, tq = 0.0f;
        for (int i = 0; i < 16; ++i) { ts += ls[i]; tq += lq[i]; }
        float mean = ts / n_total;
        float var = tq / n_total - mean * mean;
        float scale = rsqrtf(var + 1e-5f) * lnw[0];
        so[0] = scale;
        so[1] = lnb[0] - mean * scale;
    }
}

// 32B/thread (2x float4): halves block count vs 16B/thread.
__global__ void norm_kernel(float* __restrict__ x, int n8, const float* __restrict__ so) {
    int i = blockIdx.x * blockDim.x + threadIdx.x;
    if (i >= n8) return;
    float scale = so[0], off = so[1];
    float4* x4 = (float4*)x;
    float4 a = x4[2 * i];
    float4 b = x4[2 * i + 1];
    a.x = a.x * scale + off; a.y = a.y * scale + off;
    a.z = a.z * scale + off; a.w = a.w * scale + off;
    b.x = b.x * scale + off; b.y = b.y * scale + off;
    b.z = b.z * scale + off; b.w = b.w * scale + off;
    x4[2 * i] = a;
    x4[2 * i + 1] = b;
}

extern "C" void kernel_launch(void* const* d_in, const int* in_sizes, int n_in,
                              void* d_out, int out_size, void* d_ws, size_t ws_size,
                              hipStream_t stream) {
    const float* X   = (const float*)d_in[0];
    const int*   edg = (const int*)d_in[1];   // [2,E]: src row then dst row
    const float* W1  = (const float*)d_in[2];
    const float* b1  = (const float*)d_in[3];
    const float* W2  = (const float*)d_in[4];
    const float* b2  = (const float*)d_in[5];
    const float* lnw = (const float*)d_in[6];
    const float* lnb = (const float*)d_in[7];
    float* out = (float*)d_out;

    const int N  = in_sizes[0] / CH;   // 100000
    const int E  = in_sizes[1] / 2;    // 1600000
    const int NC = N * CH;             // 6.4M
    const int nNodeBlk = (N + 3) / 4;  // 25000 (4 nodes / block)
    const int nb = (N + 511) >> BSH;   // 196 buckets
    const int nblkE = (E + CHUNK - 1) / CHUNK;  // 98 edge-chunk blocks
    const int nvblk = nblkE * NREP;    // 392 virtual hist blocks

    const int* srcp = edg;
    const int* dstp = edg + E;

    // workspace layout (4B units).  R12 ALIGNMENT RULE: rs padded to N+32
    // words so dis/xws1/xws2/h stay 128B-aligned (E, N, NC all multiples of
    // 32).  R10's rs=N+1 shifted xws by 4B -> every 128B row straddled two
    // cache lines -> FETCH 88->157MB.
    int*   col   = (int*)d_ws;                          // E (aligned)
    int*   rs    = col + E;                             // N+1 used, N+32 reserved
    float* dis   = (float*)(rs + N + 32);               // N (aligned)
    __hip_bfloat16* xws1 = (__hip_bfloat16*)(dis + N);  // NC bf16 (128B rows)
    __hip_bfloat16* xws2 = xws1 + NC;                   // NC bf16 (128B rows)
    float* h     = (float*)(xws2 + NC);                 // NC floats (256B rows)
    unsigned* pairs = (unsigned*)h;                     // E u32 (dead before h live)
    int*   bHist = (int*)(h + NC);                      // nvblk*nb
    int*   bStart= bHist + nvblk * nb;                  // nb+1
    float* sums  = (float*)(bStart + nb + 1);           // nNodeBlk
    float* sqs   = sums + nNodeBlk;                     // nNodeBlk
    float* so    = sqs + nNodeBlk;                      // 2 {scale, offset}

    const int B = 256;
    const int nGemmBlk = (N + 127) / 128;               // 782 (4 rows/thread)

    // ---- CSR build (no global atomics, no memset) ----
    coarse_hist_kernel<<<nblkE, 1024, 0, stream>>>(dstp, bHist, E, nb);
    scan_hist_kernel<<<1, 1024, 0, stream>>>(bHist, bStart, nvblk, nb);
    scatter_pairs_kernel<<<nblkE, 1024, 0, stream>>>(srcp, dstp, bHist, pairs, E, nb);
    bucket_csr_kernel<<<nb, 1024, 0, stream>>>(pairs, bStart, col, rs, dis, N, nb, E);
    // rs = row_start; row i spans [rs[i], rs[i+1]); rs[N] = E

    // ---- layer 1 ----
    gemm64_scaled_kernel<<<nGemmBlk, B, 0, stream>>>(X, W1, dis, xws1, N);
    gather_pair_kernel<<<nNodeBlk, B, 0, stream>>>((const unsigned*)xws1, col, rs, dis,
                                                   b1, h, N, E);

    // ---- layer 2 ----
    gemm64_scaled_kernel<<<nGemmBlk, B, 0, stream>>>(h, W2, dis, xws2, N);
    gather_stats_kernel<<<nNodeBlk, B, 0, stream>>>((const unsigned*)xws2, col, rs, dis,
                                                    b2, out, N, E, sums, sqs);

    // ---- graph layernorm ----
    reduce_final_kernel<<<1, 1024, 0, stream>>>(sums, sqs, nNodeBlk, (float)NC, lnw, lnb, so);
    norm_kernel<<<(NC / 8 + B - 1) / B, B, 0, stream>>>(out, NC / 8, so);
}